// Round 1
// baseline (2779.462 us; speedup 1.0000x reference)
//
#include <hip/hip_runtime.h>

// LSTM_73512660239038: 64-step LSTM, H=B=1024, INPUT_DIM=1.
// Strategy: bf16x3 split GEMMs (w=whi+wlo, h=hhi+hlo, 3 MFMA passes -> fp32-level
// accuracy) + fused per-step kernel (gate GEMM + elementwise) + final projection.

typedef unsigned short ushort_t;
typedef __attribute__((ext_vector_type(8))) __bf16 bf16x8;
typedef __attribute__((ext_vector_type(4))) float f32x4;

typedef const __attribute__((address_space(1))) unsigned char* gbl_ptr_t;
typedef __attribute__((address_space(3))) unsigned char* lds_ptr_t;

__device__ __forceinline__ unsigned short f2bf(float f) {
  unsigned u = __float_as_uint(f);
  u += 0x7FFFu + ((u >> 16) & 1u);   // RNE
  return (unsigned short)(u >> 16);
}
__device__ __forceinline__ float bf2f(unsigned short b) {
  return __uint_as_float(((unsigned)b) << 16);
}
__device__ __forceinline__ float fsig(float z) {
  return 1.0f / (1.0f + __expf(-z));
}
__device__ __forceinline__ float ftanh(float z) {
  float a = fabsf(z);
  float e = __expf(-2.0f * a);
  float t = (1.0f - e) / (1.0f + e);
  return z < 0.0f ? -t : t;
}

// ---------------- prep: split weights into bf16 hi/lo ----------------
__global__ __launch_bounds__(256) void k_prep(
    const float* __restrict__ wg, const float* __restrict__ wi,
    const float* __restrict__ wf, const float* __restrict__ wo,
    const float* __restrict__ wp,
    ushort_t* __restrict__ Whi, ushort_t* __restrict__ Wlo,
    float* __restrict__ w0,
    ushort_t* __restrict__ WPhi, ushort_t* __restrict__ WPlo) {
  const int NW = 4 * 1024 * 1025;           // gate weights incl. x column
  const int NP = 1024 * 1024;               // w_p
  int i = blockIdx.x * blockDim.x + threadIdx.x;
  const int stride = gridDim.x * blockDim.x;
  for (; i < NW + NP; i += stride) {
    if (i < NW) {
      const int gate = i / (1024 * 1025);
      const int rem = i - gate * (1024 * 1025);
      const int r = rem / 1025;
      const int k = rem - r * 1025;
      const float* w = gate == 0 ? wg : gate == 1 ? wi : gate == 2 ? wf : wo;
      const float v = w[rem];
      if (k == 0) {
        w0[gate * 1024 + r] = v;            // x-weight column, kept fp32
      } else {
        const int idx = (gate * 1024 + r) * 1024 + (k - 1);
        const unsigned short h = f2bf(v);
        Whi[idx] = h;
        Wlo[idx] = f2bf(v - bf2f(h));
      }
    } else {
      const int j = i - NW;
      const float v = wp[j];
      const unsigned short h = f2bf(v);
      WPhi[j] = h;
      WPlo[j] = f2bf(v - bf2f(h));
    }
  }
}

// ---------------- per-step fused kernel ----------------
// grid 256: hrtile = bx&31 (32 h-rows), btile = bx>>5 (128 batch cols).
// 4 waves = 4 gates; wave-tile 32x128; BK=64; 3-pass bf16x3.
// LDS 64KB: staging {Ahi,Alo,Bhi,Blo}[128][64]bf16 (16KB each), then reused
// as z-exchange [4 gates][128 b][32 r] fp32.
__global__ __launch_bounds__(256) void k_step(
    const ushort_t* __restrict__ Whi, const ushort_t* __restrict__ Wlo,
    const float* __restrict__ w0,
    const float* __restrict__ x,
    const float* __restrict__ bg, const float* __restrict__ bi,
    const float* __restrict__ bff, const float* __restrict__ bo,
    const ushort_t* __restrict__ Hhi, const ushort_t* __restrict__ Hlo,
    ushort_t* __restrict__ Ohi, ushort_t* __restrict__ Olo,
    float* __restrict__ c, int t) {
  __shared__ alignas(16) unsigned char smem[65536];
  const int tid = threadIdx.x;
  const int wid = tid >> 6;                 // wave = gate
  const int lane = tid & 63;
  const int hr0 = (blockIdx.x & 31) * 32;
  const int b0 = (blockIdx.x >> 5) * 128;

  f32x4 acc[2][8];
#pragma unroll
  for (int m = 0; m < 2; ++m)
#pragma unroll
    for (int n = 0; n < 8; ++n) acc[m][n] = (f32x4){0.f, 0.f, 0.f, 0.f};

  for (int kt = 0; kt < 16; ++kt) {
    const int k0 = kt << 6;
    __syncthreads();
    // stage 4 tiles; XOR-swizzle applied on the GLOBAL source (lds dest linear)
#pragma unroll
    for (int j = 0; j < 4; ++j) {
      const int i = wid * 4 + j;            // 0..15 wave-issues per tile
      const int ch = i * 64 + lane;         // chunk 0..1023 (16B each)
      const int row = ch >> 3;              // tile row 0..127
      const int sl = ch & 7;                // lds 16B slot in row
      const int sg = sl ^ (row & 7);        // swizzled global slot
      const int gate = row >> 5, rin = row & 31;
      const long aoff = ((long)(gate * 1024 + hr0 + rin) << 10) + k0 + sg * 8;
      const long boff = ((long)(b0 + row) << 10) + k0 + sg * 8;
      __builtin_amdgcn_global_load_lds((gbl_ptr_t)(const void*)(Whi + aoff),
                                       (lds_ptr_t)(void*)(smem + i * 1024), 16, 0, 0);
      __builtin_amdgcn_global_load_lds((gbl_ptr_t)(const void*)(Wlo + aoff),
                                       (lds_ptr_t)(void*)(smem + 16384 + i * 1024), 16, 0, 0);
      __builtin_amdgcn_global_load_lds((gbl_ptr_t)(const void*)(Hhi + boff),
                                       (lds_ptr_t)(void*)(smem + 32768 + i * 1024), 16, 0, 0);
      __builtin_amdgcn_global_load_lds((gbl_ptr_t)(const void*)(Hlo + boff),
                                       (lds_ptr_t)(void*)(smem + 49152 + i * 1024), 16, 0, 0);
    }
    __syncthreads();
#pragma unroll
    for (int ks = 0; ks < 2; ++ks) {
      const int slot = (ks << 2) + (lane >> 4);
      bf16x8 aH[2], aL[2];
#pragma unroll
      for (int m = 0; m < 2; ++m) {
        const int tr = wid * 32 + m * 16 + (lane & 15);
        const int off = tr * 128 + ((slot ^ (tr & 7)) << 4);
        aH[m] = *(const bf16x8*)(smem + off);
        aL[m] = *(const bf16x8*)(smem + 16384 + off);
      }
#pragma unroll
      for (int n = 0; n < 8; ++n) {
        const int tr = n * 16 + (lane & 15);
        const int off = tr * 128 + ((slot ^ (tr & 7)) << 4);
        const bf16x8 bH = *(const bf16x8*)(smem + 32768 + off);
        const bf16x8 bL = *(const bf16x8*)(smem + 49152 + off);
#pragma unroll
        for (int m = 0; m < 2; ++m) {
          acc[m][n] = __builtin_amdgcn_mfma_f32_16x16x32_bf16(aH[m], bH, acc[m][n], 0, 0, 0);
          acc[m][n] = __builtin_amdgcn_mfma_f32_16x16x32_bf16(aH[m], bL, acc[m][n], 0, 0, 0);
          acc[m][n] = __builtin_amdgcn_mfma_f32_16x16x32_bf16(aL[m], bH, acc[m][n], 0, 0, 0);
        }
      }
    }
  }
  __syncthreads();
  // ---- z exchange through LDS (swizzled r index to dodge bank conflicts) ----
  float* zl = (float*)smem;                 // [4][128][32] fp32
#pragma unroll
  for (int n = 0; n < 8; ++n) {
    const int b = n * 16 + (lane & 15);
#pragma unroll
    for (int m = 0; m < 2; ++m) {
#pragma unroll
      for (int j = 0; j < 4; ++j) {
        const int r = m * 16 + (lane >> 4) * 4 + j;
        const int rs = (r ^ ((b & 7) << 2)) ^ ((b >> 3) & 1);
        zl[wid * 4096 + b * 32 + rs] = acc[m][n][j];
      }
    }
  }
  __syncthreads();
  // ---- elementwise gates; NOTE bias indexed by BATCH column (ref quirk) ----
  for (int q = 0; q < 16; ++q) {
    const int idx = q * 256 + tid;
    const int r = idx & 31, bb = idx >> 5;
    const int rs = (r ^ ((bb & 7) << 2)) ^ ((bb >> 3) & 1);
    const int gb = b0 + bb;                 // global batch
    const int gr = hr0 + r;                 // global h-row
    float zg = zl[bb * 32 + rs];
    float zi = zl[4096 + bb * 32 + rs];
    float zf = zl[8192 + bb * 32 + rs];
    float zo = zl[12288 + bb * 32 + rs];
    const float xv = x[gb * 64 + t];
    zg += w0[gr] * xv + bg[gb];
    zi += w0[1024 + gr] * xv + bi[gb];
    zf += w0[2048 + gr] * xv + bff[gb];
    zo += w0[3072 + gr] * xv + bo[gb];
    const float g = ftanh(zg), ii = fsig(zi), ff = fsig(zf), oo = fsig(zo);
    const long ci = (long)gb * 1024 + gr;   // c and h stored [B][H]
    const float c2 = g * ii + c[ci] * ff;
    c[ci] = c2;
    const float h2 = ftanh(c2) * oo;
    const unsigned short hh = f2bf(h2);
    Ohi[ci] = hh;
    Olo[ci] = f2bf(h2 - bf2f(hh));
  }
}

// ---------------- final projection: out[b][r] = hs[b,:]·wp[r,:] + bp[r] ----------------
__global__ __launch_bounds__(256) void k_proj(
    const ushort_t* __restrict__ Hhi, const ushort_t* __restrict__ Hlo,
    const ushort_t* __restrict__ WPhi, const ushort_t* __restrict__ WPlo,
    const float* __restrict__ bp, float* __restrict__ out) {
  __shared__ alignas(16) unsigned char smem[65536];
  const int tid = threadIdx.x;
  const int wid = tid >> 6;
  const int lane = tid & 63;
  const int b0 = (blockIdx.x >> 3) * 128;   // M = batch
  const int r0 = (blockIdx.x & 7) * 128;    // N = output row

  f32x4 acc[2][8];
#pragma unroll
  for (int m = 0; m < 2; ++m)
#pragma unroll
    for (int n = 0; n < 8; ++n) acc[m][n] = (f32x4){0.f, 0.f, 0.f, 0.f};

  for (int kt = 0; kt < 16; ++kt) {
    const int k0 = kt << 6;
    __syncthreads();
#pragma unroll
    for (int j = 0; j < 4; ++j) {
      const int i = wid * 4 + j;
      const int ch = i * 64 + lane;
      const int row = ch >> 3;
      const int sl = ch & 7;
      const int sg = sl ^ (row & 7);
      const long aoff = ((long)(b0 + row) << 10) + k0 + sg * 8;
      const long boff = ((long)(r0 + row) << 10) + k0 + sg * 8;
      __builtin_amdgcn_global_load_lds((gbl_ptr_t)(const void*)(Hhi + aoff),
                                       (lds_ptr_t)(void*)(smem + i * 1024), 16, 0, 0);
      __builtin_amdgcn_global_load_lds((gbl_ptr_t)(const void*)(Hlo + aoff),
                                       (lds_ptr_t)(void*)(smem + 16384 + i * 1024), 16, 0, 0);
      __builtin_amdgcn_global_load_lds((gbl_ptr_t)(const void*)(WPhi + boff),
                                       (lds_ptr_t)(void*)(smem + 32768 + i * 1024), 16, 0, 0);
      __builtin_amdgcn_global_load_lds((gbl_ptr_t)(const void*)(WPlo + boff),
                                       (lds_ptr_t)(void*)(smem + 49152 + i * 1024), 16, 0, 0);
    }
    __syncthreads();
#pragma unroll
    for (int ks = 0; ks < 2; ++ks) {
      const int slot = (ks << 2) + (lane >> 4);
      bf16x8 aH[2], aL[2];
#pragma unroll
      for (int m = 0; m < 2; ++m) {
        const int tr = wid * 32 + m * 16 + (lane & 15);
        const int off = tr * 128 + ((slot ^ (tr & 7)) << 4);
        aH[m] = *(const bf16x8*)(smem + off);
        aL[m] = *(const bf16x8*)(smem + 16384 + off);
      }
#pragma unroll
      for (int n = 0; n < 8; ++n) {
        const int tr = n * 16 + (lane & 15);
        const int off = tr * 128 + ((slot ^ (tr & 7)) << 4);
        const bf16x8 bH = *(const bf16x8*)(smem + 32768 + off);
        const bf16x8 bL = *(const bf16x8*)(smem + 49152 + off);
#pragma unroll
        for (int m = 0; m < 2; ++m) {
          acc[m][n] = __builtin_amdgcn_mfma_f32_16x16x32_bf16(aH[m], bH, acc[m][n], 0, 0, 0);
          acc[m][n] = __builtin_amdgcn_mfma_f32_16x16x32_bf16(aH[m], bL, acc[m][n], 0, 0, 0);
          acc[m][n] = __builtin_amdgcn_mfma_f32_16x16x32_bf16(aL[m], bH, acc[m][n], 0, 0, 0);
        }
      }
    }
  }
#pragma unroll
  for (int n = 0; n < 8; ++n) {
    const int rr = r0 + n * 16 + (lane & 15);
    const float bpv = bp[rr];
#pragma unroll
    for (int m = 0; m < 2; ++m) {
#pragma unroll
      for (int j = 0; j < 4; ++j) {
        const int bbb = b0 + wid * 32 + m * 16 + (lane >> 4) * 4 + j;
        out[(long)bbb * 1024 + rr] = acc[m][n][j] + bpv;
      }
    }
  }
}

extern "C" void kernel_launch(void* const* d_in, const int* in_sizes, int n_in,
                              void* d_out, int out_size, void* d_ws, size_t ws_size,
                              hipStream_t stream) {
  (void)in_sizes; (void)n_in; (void)out_size; (void)ws_size;
  const float* x  = (const float*)d_in[0];
  const float* wg = (const float*)d_in[1];
  const float* bg = (const float*)d_in[2];
  const float* wi = (const float*)d_in[3];
  const float* bi = (const float*)d_in[4];
  const float* wf = (const float*)d_in[5];
  const float* bf = (const float*)d_in[6];
  const float* wo = (const float*)d_in[7];
  const float* bo = (const float*)d_in[8];
  const float* wp = (const float*)d_in[9];
  const float* bp = (const float*)d_in[10];

  char* ws = (char*)d_ws;
  size_t off = 0;
  auto alloc = [&](size_t bytes) {
    char* p = ws + off;
    off += (bytes + 255) & ~(size_t)255;
    return p;
  };
  ushort_t* Whi  = (ushort_t*)alloc(8388608);   // [4096][1024] bf16 hi
  ushort_t* Wlo  = (ushort_t*)alloc(8388608);
  ushort_t* WPhi = (ushort_t*)alloc(2097152);   // [1024][1024]
  ushort_t* WPlo = (ushort_t*)alloc(2097152);
  float*    w0   = (float*)alloc(16384);        // [4][1024] x-weight col
  ushort_t* h0hi = (ushort_t*)alloc(2097152);   // h stored [B][H]
  ushort_t* h0lo = (ushort_t*)alloc(2097152);
  ushort_t* h1hi = (ushort_t*)alloc(2097152);
  ushort_t* h1lo = (ushort_t*)alloc(2097152);
  float*    c    = (float*)alloc(4194304);      // [B][H] fp32

  hipMemsetAsync(h0hi, 0, 2097152, stream);
  hipMemsetAsync(h0lo, 0, 2097152, stream);
  hipMemsetAsync(c, 0, 4194304, stream);

  k_prep<<<2048, 256, 0, stream>>>(wg, wi, wf, wo, wp, Whi, Wlo, w0, WPhi, WPlo);

  for (int t = 0; t < 64; ++t) {
    const ushort_t* ih = (t & 1) ? h1hi : h0hi;
    const ushort_t* il = (t & 1) ? h1lo : h0lo;
    ushort_t* oh = (t & 1) ? h0hi : h1hi;
    ushort_t* ol = (t & 1) ? h0lo : h1lo;
    k_step<<<256, 256, 0, stream>>>(Whi, Wlo, w0, x, bg, bi, bf, bo,
                                    ih, il, oh, ol, c, t);
  }
  // after t=63 (odd) the freshest h lives in buffer 0
  k_proj<<<64, 256, 0, stream>>>(h0hi, h0lo, WPhi, WPlo, bp, (float*)d_out);
}

// Round 2
// 2100.277 us; speedup vs baseline: 1.3234x; 1.3234x over previous
//
#include <hip/hip_runtime.h>

// LSTM_73512660239038: 64-step LSTM, H=B=1024, INPUT_DIM=1.
// bf16x3 split GEMMs (w=whi+wlo, h=hhi+hlo, 3 MFMA passes -> fp32-level accuracy).
// R2: k_step restructured to 8 waves/block (2 waves/SIMD) + double-buffered
// 128KB LDS with stage-ahead (minimum 2-phase schedule, 1 barrier/K-iter).

typedef unsigned short ushort_t;
typedef __attribute__((ext_vector_type(8))) __bf16 bf16x8;
typedef __attribute__((ext_vector_type(4))) float f32x4;

typedef const __attribute__((address_space(1))) unsigned char* gbl_ptr_t;
typedef __attribute__((address_space(3))) unsigned char* lds_ptr_t;

__device__ __forceinline__ unsigned short f2bf(float f) {
  unsigned u = __float_as_uint(f);
  u += 0x7FFFu + ((u >> 16) & 1u);   // RNE
  return (unsigned short)(u >> 16);
}
__device__ __forceinline__ float bf2f(unsigned short b) {
  return __uint_as_float(((unsigned)b) << 16);
}
__device__ __forceinline__ float fsig(float z) {
  return 1.0f / (1.0f + __expf(-z));
}
__device__ __forceinline__ float ftanh(float z) {
  float a = fabsf(z);
  float e = __expf(-2.0f * a);
  float t = (1.0f - e) / (1.0f + e);
  return z < 0.0f ? -t : t;
}

// ---------------- prep: split weights into bf16 hi/lo ----------------
__global__ __launch_bounds__(256) void k_prep(
    const float* __restrict__ wg, const float* __restrict__ wi,
    const float* __restrict__ wf, const float* __restrict__ wo,
    const float* __restrict__ wp,
    ushort_t* __restrict__ Whi, ushort_t* __restrict__ Wlo,
    float* __restrict__ w0,
    ushort_t* __restrict__ WPhi, ushort_t* __restrict__ WPlo) {
  const int NW = 4 * 1024 * 1025;
  const int NP = 1024 * 1024;
  int i = blockIdx.x * blockDim.x + threadIdx.x;
  const int stride = gridDim.x * blockDim.x;
  for (; i < NW + NP; i += stride) {
    if (i < NW) {
      const int gate = i / (1024 * 1025);
      const int rem = i - gate * (1024 * 1025);
      const int r = rem / 1025;
      const int k = rem - r * 1025;
      const float* w = gate == 0 ? wg : gate == 1 ? wi : gate == 2 ? wf : wo;
      const float v = w[rem];
      if (k == 0) {
        w0[gate * 1024 + r] = v;
      } else {
        const int idx = (gate * 1024 + r) * 1024 + (k - 1);
        const unsigned short h = f2bf(v);
        Whi[idx] = h;
        Wlo[idx] = f2bf(v - bf2f(h));
      }
    } else {
      const int j = i - NW;
      const float v = wp[j];
      const unsigned short h = f2bf(v);
      WPhi[j] = h;
      WPlo[j] = f2bf(v - bf2f(h));
    }
  }
}

// ---------------- per-step fused kernel (R2: 8 waves, dbuf) ----------------
// grid 256: hrtile = bx&31 (32 h-rows), btile = bx>>5 (128 batch cols).
// 8 waves: wave w = (gate = w>>1, row-half = w&1) -> 16x128 z-tile each.
// BK=64, bf16x3. LDS 128KB: 2 buffer sets x {Ahi,Alo,Bhi,Blo}[128][64]bf16.
__global__ __launch_bounds__(512) void k_step(
    const ushort_t* __restrict__ Whi, const ushort_t* __restrict__ Wlo,
    const float* __restrict__ w0,
    const float* __restrict__ x,
    const float* __restrict__ bg, const float* __restrict__ bi,
    const float* __restrict__ bff, const float* __restrict__ bo,
    const ushort_t* __restrict__ Hhi, const ushort_t* __restrict__ Hlo,
    ushort_t* __restrict__ Ohi, ushort_t* __restrict__ Olo,
    float* __restrict__ c, int t) {
  __shared__ alignas(16) unsigned char smem[131072];
  const int tid = threadIdx.x;
  const int wid = tid >> 6;
  const int lane = tid & 63;
  const int gate = wid >> 1;
  const int rh = wid & 1;
  const int hr0 = (blockIdx.x & 31) * 32;
  const int b0 = (blockIdx.x >> 5) * 128;

  // staging address precompute: chunks ch = s*512+tid, s=0..1 (1024 x 16B per tensor)
  long aoffb[2], boffb[2];
  int ldso[2];
#pragma unroll
  for (int s = 0; s < 2; ++s) {
    const int ch = s * 512 + tid;
    const int row = ch >> 3;
    const int sl = ch & 7;
    const int sg = sl ^ (row & 7);          // swizzle on the GLOBAL source
    const int gt = row >> 5, rin = row & 31;
    aoffb[s] = ((long)(gt * 1024 + hr0 + rin) << 10) + sg * 8;
    boffb[s] = ((long)(b0 + row) << 10) + sg * 8;
    ldso[s] = ch * 16;
  }

  f32x4 acc[8];
#pragma unroll
  for (int n = 0; n < 8; ++n) acc[n] = (f32x4){0.f, 0.f, 0.f, 0.f};

  const int tra = gate * 32 + rh * 16 + (lane & 15);
  const int abase = tra * 128;

  // prologue: stage buffer 0, k0=0
#pragma unroll
  for (int s = 0; s < 2; ++s) {
    __builtin_amdgcn_global_load_lds((gbl_ptr_t)(const void*)(Whi + aoffb[s]),
                                     (lds_ptr_t)(void*)(smem + ldso[s]), 16, 0, 0);
    __builtin_amdgcn_global_load_lds((gbl_ptr_t)(const void*)(Wlo + aoffb[s]),
                                     (lds_ptr_t)(void*)(smem + 16384 + ldso[s]), 16, 0, 0);
    __builtin_amdgcn_global_load_lds((gbl_ptr_t)(const void*)(Hhi + boffb[s]),
                                     (lds_ptr_t)(void*)(smem + 32768 + ldso[s]), 16, 0, 0);
    __builtin_amdgcn_global_load_lds((gbl_ptr_t)(const void*)(Hlo + boffb[s]),
                                     (lds_ptr_t)(void*)(smem + 49152 + ldso[s]), 16, 0, 0);
  }
  __syncthreads();   // implicit vmcnt(0): buffer 0 ready

  for (int kt = 0; kt < 16; ++kt) {
    const unsigned pb = (kt & 1) * 65536;
    // ---- stage next K-tile into the other buffer (issued BEFORE compute) ----
    if (kt < 15) {
      const unsigned nb = ((kt + 1) & 1) * 65536;
      const int k0 = (kt + 1) << 6;
#pragma unroll
      for (int s = 0; s < 2; ++s) {
        __builtin_amdgcn_global_load_lds((gbl_ptr_t)(const void*)(Whi + aoffb[s] + k0),
                                         (lds_ptr_t)(void*)(smem + nb + ldso[s]), 16, 0, 0);
        __builtin_amdgcn_global_load_lds((gbl_ptr_t)(const void*)(Wlo + aoffb[s] + k0),
                                         (lds_ptr_t)(void*)(smem + nb + 16384 + ldso[s]), 16, 0, 0);
        __builtin_amdgcn_global_load_lds((gbl_ptr_t)(const void*)(Hhi + boffb[s] + k0),
                                         (lds_ptr_t)(void*)(smem + nb + 32768 + ldso[s]), 16, 0, 0);
        __builtin_amdgcn_global_load_lds((gbl_ptr_t)(const void*)(Hlo + boffb[s] + k0),
                                         (lds_ptr_t)(void*)(smem + nb + 49152 + ldso[s]), 16, 0, 0);
      }
    }
    // ---- compute current buffer ----
#pragma unroll
    for (int ks = 0; ks < 2; ++ks) {
      const int slot = (ks << 2) + (lane >> 4);
      const int offa = abase + ((slot ^ (tra & 7)) << 4);
      const bf16x8 aH = *(const bf16x8*)(smem + pb + offa);
      const bf16x8 aL = *(const bf16x8*)(smem + pb + 16384 + offa);
#pragma unroll
      for (int n = 0; n < 8; ++n) {
        const int trb = n * 16 + (lane & 15);
        const int offb = trb * 128 + ((slot ^ (trb & 7)) << 4);
        const bf16x8 bH = *(const bf16x8*)(smem + pb + 32768 + offb);
        const bf16x8 bL = *(const bf16x8*)(smem + pb + 49152 + offb);
        acc[n] = __builtin_amdgcn_mfma_f32_16x16x32_bf16(aH, bH, acc[n], 0, 0, 0);
        acc[n] = __builtin_amdgcn_mfma_f32_16x16x32_bf16(aH, bL, acc[n], 0, 0, 0);
        acc[n] = __builtin_amdgcn_mfma_f32_16x16x32_bf16(aL, bH, acc[n], 0, 0, 0);
      }
    }
    __syncthreads();   // next buffer ready; current buffer safe to overwrite
  }

  // ---- z exchange through LDS (swizzled r to dodge bank conflicts) ----
  float* zl = (float*)smem;                 // [4 gates][128 b][32 r] fp32 = 64KB
#pragma unroll
  for (int n = 0; n < 8; ++n) {
    const int b = n * 16 + (lane & 15);
#pragma unroll
    for (int j = 0; j < 4; ++j) {
      const int r = rh * 16 + (lane >> 4) * 4 + j;
      const int rs = (r ^ ((b & 7) << 2)) ^ ((b >> 3) & 1);
      zl[gate * 4096 + b * 32 + rs] = acc[n][j];
    }
  }
  __syncthreads();
  // ---- elementwise gates; bias indexed by BATCH column (ref quirk) ----
  for (int q = 0; q < 8; ++q) {
    const int idx = q * 512 + tid;
    const int r = idx & 31, bb = idx >> 5;
    const int rs = (r ^ ((bb & 7) << 2)) ^ ((bb >> 3) & 1);
    const int gb = b0 + bb;
    const int gr = hr0 + r;
    float zg = zl[bb * 32 + rs];
    float zi = zl[4096 + bb * 32 + rs];
    float zf = zl[8192 + bb * 32 + rs];
    float zo = zl[12288 + bb * 32 + rs];
    const float xv = x[gb * 64 + t];
    zg += w0[gr] * xv + bg[gb];
    zi += w0[1024 + gr] * xv + bi[gb];
    zf += w0[2048 + gr] * xv + bff[gb];
    zo += w0[3072 + gr] * xv + bo[gb];
    const float g = ftanh(zg), ii = fsig(zi), ff = fsig(zf), oo = fsig(zo);
    const long ci = (long)gb * 1024 + gr;   // c and h stored [B][H]
    const float c2 = g * ii + c[ci] * ff;
    c[ci] = c2;
    const float h2 = ftanh(c2) * oo;
    const unsigned short hh = f2bf(h2);
    Ohi[ci] = hh;
    Olo[ci] = f2bf(h2 - bf2f(hh));
  }
}

// ---------------- final projection: out[b][r] = hs[b,:]·wp[r,:] + bp[r] ----------------
__global__ __launch_bounds__(256) void k_proj(
    const ushort_t* __restrict__ Hhi, const ushort_t* __restrict__ Hlo,
    const ushort_t* __restrict__ WPhi, const ushort_t* __restrict__ WPlo,
    const float* __restrict__ bp, float* __restrict__ out) {
  __shared__ alignas(16) unsigned char smem[65536];
  const int tid = threadIdx.x;
  const int wid = tid >> 6;
  const int lane = tid & 63;
  const int b0 = (blockIdx.x >> 3) * 128;   // M = batch
  const int r0 = (blockIdx.x & 7) * 128;    // N = output row

  f32x4 acc[2][8];
#pragma unroll
  for (int m = 0; m < 2; ++m)
#pragma unroll
    for (int n = 0; n < 8; ++n) acc[m][n] = (f32x4){0.f, 0.f, 0.f, 0.f};

  for (int kt = 0; kt < 16; ++kt) {
    const int k0 = kt << 6;
    __syncthreads();
#pragma unroll
    for (int j = 0; j < 4; ++j) {
      const int i = wid * 4 + j;
      const int ch = i * 64 + lane;
      const int row = ch >> 3;
      const int sl = ch & 7;
      const int sg = sl ^ (row & 7);
      const long aoff = ((long)(b0 + row) << 10) + k0 + sg * 8;
      const long boff = ((long)(r0 + row) << 10) + k0 + sg * 8;
      __builtin_amdgcn_global_load_lds((gbl_ptr_t)(const void*)(Hhi + aoff),
                                       (lds_ptr_t)(void*)(smem + i * 1024), 16, 0, 0);
      __builtin_amdgcn_global_load_lds((gbl_ptr_t)(const void*)(Hlo + aoff),
                                       (lds_ptr_t)(void*)(smem + 16384 + i * 1024), 16, 0, 0);
      __builtin_amdgcn_global_load_lds((gbl_ptr_t)(const void*)(WPhi + boff),
                                       (lds_ptr_t)(void*)(smem + 32768 + i * 1024), 16, 0, 0);
      __builtin_amdgcn_global_load_lds((gbl_ptr_t)(const void*)(WPlo + boff),
                                       (lds_ptr_t)(void*)(smem + 49152 + i * 1024), 16, 0, 0);
    }
    __syncthreads();
#pragma unroll
    for (int ks = 0; ks < 2; ++ks) {
      const int slot = (ks << 2) + (lane >> 4);
      bf16x8 aH[2], aL[2];
#pragma unroll
      for (int m = 0; m < 2; ++m) {
        const int tr = wid * 32 + m * 16 + (lane & 15);
        const int off = tr * 128 + ((slot ^ (tr & 7)) << 4);
        aH[m] = *(const bf16x8*)(smem + off);
        aL[m] = *(const bf16x8*)(smem + 16384 + off);
      }
#pragma unroll
      for (int n = 0; n < 8; ++n) {
        const int tr = n * 16 + (lane & 15);
        const int off = tr * 128 + ((slot ^ (tr & 7)) << 4);
        const bf16x8 bH = *(const bf16x8*)(smem + 32768 + off);
        const bf16x8 bL = *(const bf16x8*)(smem + 49152 + off);
#pragma unroll
        for (int m = 0; m < 2; ++m) {
          acc[m][n] = __builtin_amdgcn_mfma_f32_16x16x32_bf16(aH[m], bH, acc[m][n], 0, 0, 0);
          acc[m][n] = __builtin_amdgcn_mfma_f32_16x16x32_bf16(aH[m], bL, acc[m][n], 0, 0, 0);
          acc[m][n] = __builtin_amdgcn_mfma_f32_16x16x32_bf16(aL[m], bH, acc[m][n], 0, 0, 0);
        }
      }
    }
  }
#pragma unroll
  for (int n = 0; n < 8; ++n) {
    const int rr = r0 + n * 16 + (lane & 15);
    const float bpv = bp[rr];
#pragma unroll
    for (int m = 0; m < 2; ++m) {
#pragma unroll
      for (int j = 0; j < 4; ++j) {
        const int bbb = b0 + wid * 32 + m * 16 + (lane >> 4) * 4 + j;
        out[(long)bbb * 1024 + rr] = acc[m][n][j] + bpv;
      }
    }
  }
}

extern "C" void kernel_launch(void* const* d_in, const int* in_sizes, int n_in,
                              void* d_out, int out_size, void* d_ws, size_t ws_size,
                              hipStream_t stream) {
  (void)in_sizes; (void)n_in; (void)out_size; (void)ws_size;
  const float* x  = (const float*)d_in[0];
  const float* wg = (const float*)d_in[1];
  const float* bg = (const float*)d_in[2];
  const float* wi = (const float*)d_in[3];
  const float* bi = (const float*)d_in[4];
  const float* wf = (const float*)d_in[5];
  const float* bf = (const float*)d_in[6];
  const float* wo = (const float*)d_in[7];
  const float* bo = (const float*)d_in[8];
  const float* wp = (const float*)d_in[9];
  const float* bp = (const float*)d_in[10];

  char* ws = (char*)d_ws;
  size_t off = 0;
  auto alloc = [&](size_t bytes) {
    char* p = ws + off;
    off += (bytes + 255) & ~(size_t)255;
    return p;
  };
  ushort_t* Whi  = (ushort_t*)alloc(8388608);   // [4096][1024] bf16 hi
  ushort_t* Wlo  = (ushort_t*)alloc(8388608);
  ushort_t* WPhi = (ushort_t*)alloc(2097152);   // [1024][1024]
  ushort_t* WPlo = (ushort_t*)alloc(2097152);
  float*    w0   = (float*)alloc(16384);        // [4][1024] x-weight col
  ushort_t* h0hi = (ushort_t*)alloc(2097152);   // h stored [B][H]
  ushort_t* h0lo = (ushort_t*)alloc(2097152);
  ushort_t* h1hi = (ushort_t*)alloc(2097152);
  ushort_t* h1lo = (ushort_t*)alloc(2097152);
  float*    c    = (float*)alloc(4194304);      // [B][H] fp32

  hipMemsetAsync(h0hi, 0, 2097152, stream);
  hipMemsetAsync(h0lo, 0, 2097152, stream);
  hipMemsetAsync(c, 0, 4194304, stream);

  k_prep<<<2048, 256, 0, stream>>>(wg, wi, wf, wo, wp, Whi, Wlo, w0, WPhi, WPlo);

  for (int t = 0; t < 64; ++t) {
    const ushort_t* ih = (t & 1) ? h1hi : h0hi;
    const ushort_t* il = (t & 1) ? h1lo : h0lo;
    ushort_t* oh = (t & 1) ? h0hi : h1hi;
    ushort_t* ol = (t & 1) ? h0lo : h1lo;
    k_step<<<256, 512, 0, stream>>>(Whi, Wlo, w0, x, bg, bi, bf, bo,
                                    ih, il, oh, ol, c, t);
  }
  // after t=63 (odd) the freshest h lives in buffer 0
  k_proj<<<64, 256, 0, stream>>>(h0hi, h0lo, WPhi, WPlo, bp, (float*)d_out);
}

// Round 3
// 1980.903 us; speedup vs baseline: 1.4031x; 1.0603x over previous
//
#include <hip/hip_runtime.h>

// LSTM_73512660239038: 64-step LSTM, H=B=1024, INPUT_DIM=1.
// bf16x3 split GEMMs (w=whi+wlo, h=hhi+hlo, 3 MFMA passes -> fp32-level accuracy).
// R3: k_step wave tiles 16x128 -> 32x64 (square-ish). LDS-read traffic per iter
// 294KB -> 196KB (the measured regime is LDS-BW-bound, not latency-bound).

typedef unsigned short ushort_t;
typedef __attribute__((ext_vector_type(8))) __bf16 bf16x8;
typedef __attribute__((ext_vector_type(4))) float f32x4;

typedef const __attribute__((address_space(1))) unsigned char* gbl_ptr_t;
typedef __attribute__((address_space(3))) unsigned char* lds_ptr_t;

__device__ __forceinline__ unsigned short f2bf(float f) {
  unsigned u = __float_as_uint(f);
  u += 0x7FFFu + ((u >> 16) & 1u);   // RNE
  return (unsigned short)(u >> 16);
}
__device__ __forceinline__ float bf2f(unsigned short b) {
  return __uint_as_float(((unsigned)b) << 16);
}
__device__ __forceinline__ float fsig(float z) {
  return 1.0f / (1.0f + __expf(-z));
}
__device__ __forceinline__ float ftanh(float z) {
  float a = fabsf(z);
  float e = __expf(-2.0f * a);
  float t = (1.0f - e) / (1.0f + e);
  return z < 0.0f ? -t : t;
}

// ---------------- prep: split weights into bf16 hi/lo ----------------
__global__ __launch_bounds__(256) void k_prep(
    const float* __restrict__ wg, const float* __restrict__ wi,
    const float* __restrict__ wf, const float* __restrict__ wo,
    const float* __restrict__ wp,
    ushort_t* __restrict__ Whi, ushort_t* __restrict__ Wlo,
    float* __restrict__ w0,
    ushort_t* __restrict__ WPhi, ushort_t* __restrict__ WPlo) {
  const int NW = 4 * 1024 * 1025;
  const int NP = 1024 * 1024;
  int i = blockIdx.x * blockDim.x + threadIdx.x;
  const int stride = gridDim.x * blockDim.x;
  for (; i < NW + NP; i += stride) {
    if (i < NW) {
      const int gate = i / (1024 * 1025);
      const int rem = i - gate * (1024 * 1025);
      const int r = rem / 1025;
      const int k = rem - r * 1025;
      const float* w = gate == 0 ? wg : gate == 1 ? wi : gate == 2 ? wf : wo;
      const float v = w[rem];
      if (k == 0) {
        w0[gate * 1024 + r] = v;
      } else {
        const int idx = (gate * 1024 + r) * 1024 + (k - 1);
        const unsigned short h = f2bf(v);
        Whi[idx] = h;
        Wlo[idx] = f2bf(v - bf2f(h));
      }
    } else {
      const int j = i - NW;
      const float v = wp[j];
      const unsigned short h = f2bf(v);
      WPhi[j] = h;
      WPlo[j] = f2bf(v - bf2f(h));
    }
  }
}

// ---------------- per-step fused kernel (R3: 32x64 wave tiles) ----------------
// grid 256: hrtile = bx&31 (32 h-rows), btile = bx>>5 (128 batch cols).
// 8 waves: gate = wid>>1 (A rows gate*32..+32), wn = wid&1 (B cols wn*64..+64).
// BK=64, bf16x3. LDS 128KB: 2 buffer sets x {Ahi,Alo,Bhi,Blo}[128][64]bf16.
__global__ __launch_bounds__(512) void k_step(
    const ushort_t* __restrict__ Whi, const ushort_t* __restrict__ Wlo,
    const float* __restrict__ w0,
    const float* __restrict__ x,
    const float* __restrict__ bg, const float* __restrict__ bi,
    const float* __restrict__ bff, const float* __restrict__ bo,
    const ushort_t* __restrict__ Hhi, const ushort_t* __restrict__ Hlo,
    ushort_t* __restrict__ Ohi, ushort_t* __restrict__ Olo,
    float* __restrict__ c, int t) {
  __shared__ alignas(16) unsigned char smem[131072];
  const int tid = threadIdx.x;
  const int wid = tid >> 6;
  const int lane = tid & 63;
  const int gate = wid >> 1;                // A-row group AND output gate
  const int wn = wid & 1;                   // B-col half
  const int hr0 = (blockIdx.x & 31) * 32;
  const int b0 = (blockIdx.x >> 5) * 128;

  // staging address precompute: chunks ch = s*512+tid, s=0..1 (1024 x 16B per tensor)
  long aoffb[2], boffb[2];
  int ldso[2];
#pragma unroll
  for (int s = 0; s < 2; ++s) {
    const int ch = s * 512 + tid;
    const int row = ch >> 3;
    const int sl = ch & 7;
    const int sg = sl ^ (row & 7);          // swizzle on the GLOBAL source
    const int gt = row >> 5, rin = row & 31;
    aoffb[s] = ((long)(gt * 1024 + hr0 + rin) << 10) + sg * 8;
    boffb[s] = ((long)(b0 + row) << 10) + sg * 8;
    ldso[s] = ch * 16;
  }

  f32x4 acc[2][4];
#pragma unroll
  for (int m = 0; m < 2; ++m)
#pragma unroll
    for (int n = 0; n < 4; ++n) acc[m][n] = (f32x4){0.f, 0.f, 0.f, 0.f};

  // prologue: stage buffer 0, k0=0
#pragma unroll
  for (int s = 0; s < 2; ++s) {
    __builtin_amdgcn_global_load_lds((gbl_ptr_t)(const void*)(Whi + aoffb[s]),
                                     (lds_ptr_t)(void*)(smem + ldso[s]), 16, 0, 0);
    __builtin_amdgcn_global_load_lds((gbl_ptr_t)(const void*)(Wlo + aoffb[s]),
                                     (lds_ptr_t)(void*)(smem + 16384 + ldso[s]), 16, 0, 0);
    __builtin_amdgcn_global_load_lds((gbl_ptr_t)(const void*)(Hhi + boffb[s]),
                                     (lds_ptr_t)(void*)(smem + 32768 + ldso[s]), 16, 0, 0);
    __builtin_amdgcn_global_load_lds((gbl_ptr_t)(const void*)(Hlo + boffb[s]),
                                     (lds_ptr_t)(void*)(smem + 49152 + ldso[s]), 16, 0, 0);
  }
  __syncthreads();   // implicit vmcnt(0): buffer 0 ready

  for (int kt = 0; kt < 16; ++kt) {
    const unsigned pb = (kt & 1) * 65536;
    // ---- stage next K-tile into the other buffer (issued BEFORE compute) ----
    if (kt < 15) {
      const unsigned nb = ((kt + 1) & 1) * 65536;
      const int k0 = (kt + 1) << 6;
#pragma unroll
      for (int s = 0; s < 2; ++s) {
        __builtin_amdgcn_global_load_lds((gbl_ptr_t)(const void*)(Whi + aoffb[s] + k0),
                                         (lds_ptr_t)(void*)(smem + nb + ldso[s]), 16, 0, 0);
        __builtin_amdgcn_global_load_lds((gbl_ptr_t)(const void*)(Wlo + aoffb[s] + k0),
                                         (lds_ptr_t)(void*)(smem + nb + 16384 + ldso[s]), 16, 0, 0);
        __builtin_amdgcn_global_load_lds((gbl_ptr_t)(const void*)(Hhi + boffb[s] + k0),
                                         (lds_ptr_t)(void*)(smem + nb + 32768 + ldso[s]), 16, 0, 0);
        __builtin_amdgcn_global_load_lds((gbl_ptr_t)(const void*)(Hlo + boffb[s] + k0),
                                         (lds_ptr_t)(void*)(smem + nb + 49152 + ldso[s]), 16, 0, 0);
      }
    }
    // ---- compute current buffer: wave tile 32 (A rows) x 64 (B cols) ----
#pragma unroll
    for (int ks = 0; ks < 2; ++ks) {
      const int slot = (ks << 2) + (lane >> 4);
      bf16x8 aH[2], aL[2];
#pragma unroll
      for (int m = 0; m < 2; ++m) {
        const int tra = gate * 32 + m * 16 + (lane & 15);
        const int offa = tra * 128 + ((slot ^ (tra & 7)) << 4);
        aH[m] = *(const bf16x8*)(smem + pb + offa);
        aL[m] = *(const bf16x8*)(smem + pb + 16384 + offa);
      }
#pragma unroll
      for (int n = 0; n < 4; ++n) {
        const int trb = wn * 64 + n * 16 + (lane & 15);
        const int offb = trb * 128 + ((slot ^ (trb & 7)) << 4);
        const bf16x8 bH = *(const bf16x8*)(smem + pb + 32768 + offb);
        const bf16x8 bL = *(const bf16x8*)(smem + pb + 49152 + offb);
#pragma unroll
        for (int m = 0; m < 2; ++m) {
          acc[m][n] = __builtin_amdgcn_mfma_f32_16x16x32_bf16(aH[m], bH, acc[m][n], 0, 0, 0);
          acc[m][n] = __builtin_amdgcn_mfma_f32_16x16x32_bf16(aH[m], bL, acc[m][n], 0, 0, 0);
          acc[m][n] = __builtin_amdgcn_mfma_f32_16x16x32_bf16(aL[m], bH, acc[m][n], 0, 0, 0);
        }
      }
    }
    __syncthreads();   // next buffer ready; current buffer safe to overwrite
  }

  // ---- z exchange through LDS (swizzled r to dodge bank conflicts) ----
  float* zl = (float*)smem;                 // [4 gates][128 b][32 r] fp32 = 64KB
#pragma unroll
  for (int n = 0; n < 4; ++n) {
    const int b = wn * 64 + n * 16 + (lane & 15);
#pragma unroll
    for (int m = 0; m < 2; ++m) {
#pragma unroll
      for (int j = 0; j < 4; ++j) {
        const int r = m * 16 + (lane >> 4) * 4 + j;
        const int rs = (r ^ ((b & 7) << 2)) ^ ((b >> 3) & 1);
        zl[gate * 4096 + b * 32 + rs] = acc[m][n][j];
      }
    }
  }
  __syncthreads();
  // ---- elementwise gates; bias indexed by BATCH column (ref quirk) ----
  for (int q = 0; q < 8; ++q) {
    const int idx = q * 512 + tid;
    const int r = idx & 31, bb = idx >> 5;
    const int rs = (r ^ ((bb & 7) << 2)) ^ ((bb >> 3) & 1);
    const int gb = b0 + bb;
    const int gr = hr0 + r;
    float zg = zl[bb * 32 + rs];
    float zi = zl[4096 + bb * 32 + rs];
    float zf = zl[8192 + bb * 32 + rs];
    float zo = zl[12288 + bb * 32 + rs];
    const float xv = x[gb * 64 + t];
    zg += w0[gr] * xv + bg[gb];
    zi += w0[1024 + gr] * xv + bi[gb];
    zf += w0[2048 + gr] * xv + bff[gb];
    zo += w0[3072 + gr] * xv + bo[gb];
    const float g = ftanh(zg), ii = fsig(zi), ff = fsig(zf), oo = fsig(zo);
    const long ci = (long)gb * 1024 + gr;   // c and h stored [B][H]
    const float c2 = g * ii + c[ci] * ff;
    c[ci] = c2;
    const float h2 = ftanh(c2) * oo;
    const unsigned short hh = f2bf(h2);
    Ohi[ci] = hh;
    Olo[ci] = f2bf(h2 - bf2f(hh));
  }
}

// ---------------- final projection: out[b][r] = hs[b,:]·wp[r,:] + bp[r] ----------------
__global__ __launch_bounds__(256) void k_proj(
    const ushort_t* __restrict__ Hhi, const ushort_t* __restrict__ Hlo,
    const ushort_t* __restrict__ WPhi, const ushort_t* __restrict__ WPlo,
    const float* __restrict__ bp, float* __restrict__ out) {
  __shared__ alignas(16) unsigned char smem[65536];
  const int tid = threadIdx.x;
  const int wid = tid >> 6;
  const int lane = tid & 63;
  const int b0 = (blockIdx.x >> 3) * 128;   // M = batch
  const int r0 = (blockIdx.x & 7) * 128;    // N = output row

  f32x4 acc[2][8];
#pragma unroll
  for (int m = 0; m < 2; ++m)
#pragma unroll
    for (int n = 0; n < 8; ++n) acc[m][n] = (f32x4){0.f, 0.f, 0.f, 0.f};

  for (int kt = 0; kt < 16; ++kt) {
    const int k0 = kt << 6;
    __syncthreads();
#pragma unroll
    for (int j = 0; j < 4; ++j) {
      const int i = wid * 4 + j;
      const int ch = i * 64 + lane;
      const int row = ch >> 3;
      const int sl = ch & 7;
      const int sg = sl ^ (row & 7);
      const long aoff = ((long)(b0 + row) << 10) + k0 + sg * 8;
      const long boff = ((long)(r0 + row) << 10) + k0 + sg * 8;
      __builtin_amdgcn_global_load_lds((gbl_ptr_t)(const void*)(Hhi + aoff),
                                       (lds_ptr_t)(void*)(smem + i * 1024), 16, 0, 0);
      __builtin_amdgcn_global_load_lds((gbl_ptr_t)(const void*)(Hlo + aoff),
                                       (lds_ptr_t)(void*)(smem + 16384 + i * 1024), 16, 0, 0);
      __builtin_amdgcn_global_load_lds((gbl_ptr_t)(const void*)(WPhi + boff),
                                       (lds_ptr_t)(void*)(smem + 32768 + i * 1024), 16, 0, 0);
      __builtin_amdgcn_global_load_lds((gbl_ptr_t)(const void*)(WPlo + boff),
                                       (lds_ptr_t)(void*)(smem + 49152 + i * 1024), 16, 0, 0);
    }
    __syncthreads();
#pragma unroll
    for (int ks = 0; ks < 2; ++ks) {
      const int slot = (ks << 2) + (lane >> 4);
      bf16x8 aH[2], aL[2];
#pragma unroll
      for (int m = 0; m < 2; ++m) {
        const int tr = wid * 32 + m * 16 + (lane & 15);
        const int off = tr * 128 + ((slot ^ (tr & 7)) << 4);
        aH[m] = *(const bf16x8*)(smem + off);
        aL[m] = *(const bf16x8*)(smem + 16384 + off);
      }
#pragma unroll
      for (int n = 0; n < 8; ++n) {
        const int tr = n * 16 + (lane & 15);
        const int off = tr * 128 + ((slot ^ (tr & 7)) << 4);
        const bf16x8 bH = *(const bf16x8*)(smem + 32768 + off);
        const bf16x8 bL = *(const bf16x8*)(smem + 49152 + off);
#pragma unroll
        for (int m = 0; m < 2; ++m) {
          acc[m][n] = __builtin_amdgcn_mfma_f32_16x16x32_bf16(aH[m], bH, acc[m][n], 0, 0, 0);
          acc[m][n] = __builtin_amdgcn_mfma_f32_16x16x32_bf16(aH[m], bL, acc[m][n], 0, 0, 0);
          acc[m][n] = __builtin_amdgcn_mfma_f32_16x16x32_bf16(aL[m], bH, acc[m][n], 0, 0, 0);
        }
      }
    }
  }
#pragma unroll
  for (int n = 0; n < 8; ++n) {
    const int rr = r0 + n * 16 + (lane & 15);
    const float bpv = bp[rr];
#pragma unroll
    for (int m = 0; m < 2; ++m) {
#pragma unroll
      for (int j = 0; j < 4; ++j) {
        const int bbb = b0 + wid * 32 + m * 16 + (lane >> 4) * 4 + j;
        out[(long)bbb * 1024 + rr] = acc[m][n][j] + bpv;
      }
    }
  }
}

extern "C" void kernel_launch(void* const* d_in, const int* in_sizes, int n_in,
                              void* d_out, int out_size, void* d_ws, size_t ws_size,
                              hipStream_t stream) {
  (void)in_sizes; (void)n_in; (void)out_size; (void)ws_size;
  const float* x  = (const float*)d_in[0];
  const float* wg = (const float*)d_in[1];
  const float* bg = (const float*)d_in[2];
  const float* wi = (const float*)d_in[3];
  const float* bi = (const float*)d_in[4];
  const float* wf = (const float*)d_in[5];
  const float* bf = (const float*)d_in[6];
  const float* wo = (const float*)d_in[7];
  const float* bo = (const float*)d_in[8];
  const float* wp = (const float*)d_in[9];
  const float* bp = (const float*)d_in[10];

  char* ws = (char*)d_ws;
  size_t off = 0;
  auto alloc = [&](size_t bytes) {
    char* p = ws + off;
    off += (bytes + 255) & ~(size_t)255;
    return p;
  };
  ushort_t* Whi  = (ushort_t*)alloc(8388608);   // [4096][1024] bf16 hi
  ushort_t* Wlo  = (ushort_t*)alloc(8388608);
  ushort_t* WPhi = (ushort_t*)alloc(2097152);   // [1024][1024]
  ushort_t* WPlo = (ushort_t*)alloc(2097152);
  float*    w0   = (float*)alloc(16384);        // [4][1024] x-weight col
  ushort_t* h0hi = (ushort_t*)alloc(2097152);   // h stored [B][H]
  ushort_t* h0lo = (ushort_t*)alloc(2097152);
  ushort_t* h1hi = (ushort_t*)alloc(2097152);
  ushort_t* h1lo = (ushort_t*)alloc(2097152);
  float*    c    = (float*)alloc(4194304);      // [B][H] fp32

  hipMemsetAsync(h0hi, 0, 2097152, stream);
  hipMemsetAsync(h0lo, 0, 2097152, stream);
  hipMemsetAsync(c, 0, 4194304, stream);

  k_prep<<<2048, 256, 0, stream>>>(wg, wi, wf, wo, wp, Whi, Wlo, w0, WPhi, WPlo);

  for (int t = 0; t < 64; ++t) {
    const ushort_t* ih = (t & 1) ? h1hi : h0hi;
    const ushort_t* il = (t & 1) ? h1lo : h0lo;
    ushort_t* oh = (t & 1) ? h0hi : h1hi;
    ushort_t* ol = (t & 1) ? h0lo : h1lo;
    k_step<<<256, 512, 0, stream>>>(Whi, Wlo, w0, x, bg, bi, bf, bo,
                                    ih, il, oh, ol, c, t);
  }
  // after t=63 (odd) the freshest h lives in buffer 0
  k_proj<<<64, 256, 0, stream>>>(h0hi, h0lo, WPhi, WPlo, bp, (float*)d_out);
}

// Round 4
// 1499.705 us; speedup vs baseline: 1.8533x; 1.3209x over previous
//
#include <hip/hip_runtime.h>

// LSTM_73512660239038: 64-step LSTM, H=B=1024, INPUT_DIM=1.
// R4: w = bf16 hi+lo (2 MFMA passes), h = single bf16 (h_lo DROPPED).
// LDS traffic/iter 256KB -> 176KB; LDS 96KB; error headroom spent: measured
// 4.9e-4 with h hi+lo, predicted ~2e-3 now vs 4.63e-3 threshold.

typedef unsigned short ushort_t;
typedef __attribute__((ext_vector_type(8))) __bf16 bf16x8;
typedef __attribute__((ext_vector_type(4))) float f32x4;

typedef const __attribute__((address_space(1))) unsigned char* gbl_ptr_t;
typedef __attribute__((address_space(3))) unsigned char* lds_ptr_t;

__device__ __forceinline__ unsigned short f2bf(float f) {
  unsigned u = __float_as_uint(f);
  u += 0x7FFFu + ((u >> 16) & 1u);   // RNE
  return (unsigned short)(u >> 16);
}
__device__ __forceinline__ float bf2f(unsigned short b) {
  return __uint_as_float(((unsigned)b) << 16);
}
__device__ __forceinline__ float fsig(float z) {
  return 1.0f / (1.0f + __expf(-z));
}
__device__ __forceinline__ float ftanh(float z) {
  float a = fabsf(z);
  float e = __expf(-2.0f * a);
  float t = (1.0f - e) / (1.0f + e);
  return z < 0.0f ? -t : t;
}

// ---------------- prep: split weights into bf16 hi/lo ----------------
__global__ __launch_bounds__(256) void k_prep(
    const float* __restrict__ wg, const float* __restrict__ wi,
    const float* __restrict__ wf, const float* __restrict__ wo,
    const float* __restrict__ wp,
    ushort_t* __restrict__ Whi, ushort_t* __restrict__ Wlo,
    float* __restrict__ w0,
    ushort_t* __restrict__ WPhi, ushort_t* __restrict__ WPlo) {
  const int NW = 4 * 1024 * 1025;
  const int NP = 1024 * 1024;
  int i = blockIdx.x * blockDim.x + threadIdx.x;
  const int stride = gridDim.x * blockDim.x;
  for (; i < NW + NP; i += stride) {
    if (i < NW) {
      const int gate = i / (1024 * 1025);
      const int rem = i - gate * (1024 * 1025);
      const int r = rem / 1025;
      const int k = rem - r * 1025;
      const float* w = gate == 0 ? wg : gate == 1 ? wi : gate == 2 ? wf : wo;
      const float v = w[rem];
      if (k == 0) {
        w0[gate * 1024 + r] = v;
      } else {
        const int idx = (gate * 1024 + r) * 1024 + (k - 1);
        const unsigned short h = f2bf(v);
        Whi[idx] = h;
        Wlo[idx] = f2bf(v - bf2f(h));
      }
    } else {
      const int j = i - NW;
      const float v = wp[j];
      const unsigned short h = f2bf(v);
      WPhi[j] = h;
      WPlo[j] = f2bf(v - bf2f(h));
    }
  }
}

// ---------------- per-step fused kernel (R4: 2-pass, h single bf16) ----------------
// grid 256: hrtile = bx&31 (32 h-rows), btile = bx>>5 (128 batch cols).
// 8 waves: gate = wid>>1 (A rows gate*32..+32), wn = wid&1 (B cols wn*64..+64).
// BK=64. LDS 96KB: 2 sets x {Whi,Wlo,Hhi}[128][64]bf16 (48KB/set).
__global__ __launch_bounds__(512) void k_step(
    const ushort_t* __restrict__ Whi, const ushort_t* __restrict__ Wlo,
    const float* __restrict__ w0,
    const float* __restrict__ x,
    const float* __restrict__ bg, const float* __restrict__ bi,
    const float* __restrict__ bff, const float* __restrict__ bo,
    const ushort_t* __restrict__ Hin, ushort_t* __restrict__ Hout,
    float* __restrict__ c, int t) {
  __shared__ alignas(16) unsigned char smem[98304];
  const int tid = threadIdx.x;
  const int wid = tid >> 6;
  const int lane = tid & 63;
  const int gate = wid >> 1;                // A-row group AND output gate
  const int wn = wid & 1;                   // B-col half
  const int hr0 = (blockIdx.x & 31) * 32;
  const int b0 = (blockIdx.x >> 5) * 128;

  // staging address precompute: chunks ch = s*512+tid, s=0..1 (1024 x 16B per tensor)
  long aoffb[2], boffb[2];
  int ldso[2];
#pragma unroll
  for (int s = 0; s < 2; ++s) {
    const int ch = s * 512 + tid;
    const int row = ch >> 3;
    const int sl = ch & 7;
    const int sg = sl ^ (row & 7);          // swizzle on the GLOBAL source
    const int gt = row >> 5, rin = row & 31;
    aoffb[s] = ((long)(gt * 1024 + hr0 + rin) << 10) + sg * 8;
    boffb[s] = ((long)(b0 + row) << 10) + sg * 8;
    ldso[s] = ch * 16;
  }

  f32x4 acc[2][4];
#pragma unroll
  for (int m = 0; m < 2; ++m)
#pragma unroll
    for (int n = 0; n < 4; ++n) acc[m][n] = (f32x4){0.f, 0.f, 0.f, 0.f};

  // prologue: stage buffer 0, k0=0
#pragma unroll
  for (int s = 0; s < 2; ++s) {
    __builtin_amdgcn_global_load_lds((gbl_ptr_t)(const void*)(Whi + aoffb[s]),
                                     (lds_ptr_t)(void*)(smem + ldso[s]), 16, 0, 0);
    __builtin_amdgcn_global_load_lds((gbl_ptr_t)(const void*)(Wlo + aoffb[s]),
                                     (lds_ptr_t)(void*)(smem + 16384 + ldso[s]), 16, 0, 0);
    __builtin_amdgcn_global_load_lds((gbl_ptr_t)(const void*)(Hin + boffb[s]),
                                     (lds_ptr_t)(void*)(smem + 32768 + ldso[s]), 16, 0, 0);
  }
  __syncthreads();   // implicit vmcnt(0): buffer 0 ready

  for (int kt = 0; kt < 16; ++kt) {
    const unsigned pb = (kt & 1) * 49152;
    // ---- stage next K-tile into the other buffer (issued BEFORE compute) ----
    if (kt < 15) {
      const unsigned nb = ((kt + 1) & 1) * 49152;
      const int k0 = (kt + 1) << 6;
#pragma unroll
      for (int s = 0; s < 2; ++s) {
        __builtin_amdgcn_global_load_lds((gbl_ptr_t)(const void*)(Whi + aoffb[s] + k0),
                                         (lds_ptr_t)(void*)(smem + nb + ldso[s]), 16, 0, 0);
        __builtin_amdgcn_global_load_lds((gbl_ptr_t)(const void*)(Wlo + aoffb[s] + k0),
                                         (lds_ptr_t)(void*)(smem + nb + 16384 + ldso[s]), 16, 0, 0);
        __builtin_amdgcn_global_load_lds((gbl_ptr_t)(const void*)(Hin + boffb[s] + k0),
                                         (lds_ptr_t)(void*)(smem + nb + 32768 + ldso[s]), 16, 0, 0);
      }
    }
    // ---- compute current buffer: wave tile 32 (A rows) x 64 (B cols) ----
#pragma unroll
    for (int ks = 0; ks < 2; ++ks) {
      const int slot = (ks << 2) + (lane >> 4);
      bf16x8 aH[2], aL[2];
#pragma unroll
      for (int m = 0; m < 2; ++m) {
        const int tra = gate * 32 + m * 16 + (lane & 15);
        const int offa = tra * 128 + ((slot ^ (tra & 7)) << 4);
        aH[m] = *(const bf16x8*)(smem + pb + offa);
        aL[m] = *(const bf16x8*)(smem + pb + 16384 + offa);
      }
#pragma unroll
      for (int n = 0; n < 4; ++n) {
        const int trb = wn * 64 + n * 16 + (lane & 15);
        const int offb = trb * 128 + ((slot ^ (trb & 7)) << 4);
        const bf16x8 bH = *(const bf16x8*)(smem + pb + 32768 + offb);
#pragma unroll
        for (int m = 0; m < 2; ++m) {
          acc[m][n] = __builtin_amdgcn_mfma_f32_16x16x32_bf16(aH[m], bH, acc[m][n], 0, 0, 0);
          acc[m][n] = __builtin_amdgcn_mfma_f32_16x16x32_bf16(aL[m], bH, acc[m][n], 0, 0, 0);
        }
      }
    }
    __syncthreads();   // next buffer ready; current buffer safe to overwrite
  }

  // ---- z exchange through LDS (swizzled r to dodge bank conflicts) ----
  float* zl = (float*)smem;                 // [4 gates][128 b][32 r] fp32 = 64KB
#pragma unroll
  for (int n = 0; n < 4; ++n) {
    const int b = wn * 64 + n * 16 + (lane & 15);
#pragma unroll
    for (int m = 0; m < 2; ++m) {
#pragma unroll
      for (int j = 0; j < 4; ++j) {
        const int r = m * 16 + (lane >> 4) * 4 + j;
        const int rs = (r ^ ((b & 7) << 2)) ^ ((b >> 3) & 1);
        zl[gate * 4096 + b * 32 + rs] = acc[m][n][j];
      }
    }
  }
  __syncthreads();
  // ---- elementwise gates; bias indexed by BATCH column (ref quirk) ----
  for (int q = 0; q < 8; ++q) {
    const int idx = q * 512 + tid;
    const int r = idx & 31, bb = idx >> 5;
    const int rs = (r ^ ((bb & 7) << 2)) ^ ((bb >> 3) & 1);
    const int gb = b0 + bb;
    const int gr = hr0 + r;
    float zg = zl[bb * 32 + rs];
    float zi = zl[4096 + bb * 32 + rs];
    float zf = zl[8192 + bb * 32 + rs];
    float zo = zl[12288 + bb * 32 + rs];
    const float xv = x[gb * 64 + t];
    zg += w0[gr] * xv + bg[gb];
    zi += w0[1024 + gr] * xv + bi[gb];
    zf += w0[2048 + gr] * xv + bff[gb];
    zo += w0[3072 + gr] * xv + bo[gb];
    const float g = ftanh(zg), ii = fsig(zi), ff = fsig(zf), oo = fsig(zo);
    const long ci = (long)gb * 1024 + gr;   // c and h stored [B][H]
    const float c2 = g * ii + c[ci] * ff;
    c[ci] = c2;
    const float h2 = ftanh(c2) * oo;
    Hout[ci] = f2bf(h2);
  }
}

// ---------------- final projection: out[b][r] = hs[b,:]·wp[r,:] + bp[r] ----------------
// h is single bf16; wp = hi+lo (2 passes).
__global__ __launch_bounds__(256) void k_proj(
    const ushort_t* __restrict__ H,
    const ushort_t* __restrict__ WPhi, const ushort_t* __restrict__ WPlo,
    const float* __restrict__ bp, float* __restrict__ out) {
  __shared__ alignas(16) unsigned char smem[49152];
  const int tid = threadIdx.x;
  const int wid = tid >> 6;
  const int lane = tid & 63;
  const int b0 = (blockIdx.x >> 3) * 128;   // M = batch
  const int r0 = (blockIdx.x & 7) * 128;    // N = output row

  f32x4 acc[2][8];
#pragma unroll
  for (int m = 0; m < 2; ++m)
#pragma unroll
    for (int n = 0; n < 8; ++n) acc[m][n] = (f32x4){0.f, 0.f, 0.f, 0.f};

  for (int kt = 0; kt < 16; ++kt) {
    const int k0 = kt << 6;
    __syncthreads();
#pragma unroll
    for (int j = 0; j < 4; ++j) {
      const int i = wid * 4 + j;
      const int ch = i * 64 + lane;
      const int row = ch >> 3;
      const int sl = ch & 7;
      const int sg = sl ^ (row & 7);
      const long aoff = ((long)(b0 + row) << 10) + k0 + sg * 8;
      const long boff = ((long)(r0 + row) << 10) + k0 + sg * 8;
      __builtin_amdgcn_global_load_lds((gbl_ptr_t)(const void*)(H + aoff),
                                       (lds_ptr_t)(void*)(smem + i * 1024), 16, 0, 0);
      __builtin_amdgcn_global_load_lds((gbl_ptr_t)(const void*)(WPhi + boff),
                                       (lds_ptr_t)(void*)(smem + 16384 + i * 1024), 16, 0, 0);
      __builtin_amdgcn_global_load_lds((gbl_ptr_t)(const void*)(WPlo + boff),
                                       (lds_ptr_t)(void*)(smem + 32768 + i * 1024), 16, 0, 0);
    }
    __syncthreads();
#pragma unroll
    for (int ks = 0; ks < 2; ++ks) {
      const int slot = (ks << 2) + (lane >> 4);
      bf16x8 aH[2];
#pragma unroll
      for (int m = 0; m < 2; ++m) {
        const int tr = wid * 32 + m * 16 + (lane & 15);
        const int off = tr * 128 + ((slot ^ (tr & 7)) << 4);
        aH[m] = *(const bf16x8*)(smem + off);
      }
#pragma unroll
      for (int n = 0; n < 8; ++n) {
        const int tr = n * 16 + (lane & 15);
        const int off = tr * 128 + ((slot ^ (tr & 7)) << 4);
        const bf16x8 bH = *(const bf16x8*)(smem + 16384 + off);
        const bf16x8 bL = *(const bf16x8*)(smem + 32768 + off);
#pragma unroll
        for (int m = 0; m < 2; ++m) {
          acc[m][n] = __builtin_amdgcn_mfma_f32_16x16x32_bf16(aH[m], bH, acc[m][n], 0, 0, 0);
          acc[m][n] = __builtin_amdgcn_mfma_f32_16x16x32_bf16(aH[m], bL, acc[m][n], 0, 0, 0);
        }
      }
    }
  }
#pragma unroll
  for (int n = 0; n < 8; ++n) {
    const int rr = r0 + n * 16 + (lane & 15);
    const float bpv = bp[rr];
#pragma unroll
    for (int m = 0; m < 2; ++m) {
#pragma unroll
      for (int j = 0; j < 4; ++j) {
        const int bbb = b0 + wid * 32 + m * 16 + (lane >> 4) * 4 + j;
        out[(long)bbb * 1024 + rr] = acc[m][n][j] + bpv;
      }
    }
  }
}

extern "C" void kernel_launch(void* const* d_in, const int* in_sizes, int n_in,
                              void* d_out, int out_size, void* d_ws, size_t ws_size,
                              hipStream_t stream) {
  (void)in_sizes; (void)n_in; (void)out_size; (void)ws_size;
  const float* x  = (const float*)d_in[0];
  const float* wg = (const float*)d_in[1];
  const float* bg = (const float*)d_in[2];
  const float* wi = (const float*)d_in[3];
  const float* bi = (const float*)d_in[4];
  const float* wf = (const float*)d_in[5];
  const float* bf = (const float*)d_in[6];
  const float* wo = (const float*)d_in[7];
  const float* bo = (const float*)d_in[8];
  const float* wp = (const float*)d_in[9];
  const float* bp = (const float*)d_in[10];

  char* ws = (char*)d_ws;
  size_t off = 0;
  auto alloc = [&](size_t bytes) {
    char* p = ws + off;
    off += (bytes + 255) & ~(size_t)255;
    return p;
  };
  ushort_t* Whi  = (ushort_t*)alloc(8388608);   // [4096][1024] bf16 hi
  ushort_t* Wlo  = (ushort_t*)alloc(8388608);
  ushort_t* WPhi = (ushort_t*)alloc(2097152);   // [1024][1024]
  ushort_t* WPlo = (ushort_t*)alloc(2097152);
  float*    w0   = (float*)alloc(16384);        // [4][1024] x-weight col
  ushort_t* h0   = (ushort_t*)alloc(2097152);   // h stored [B][H], single bf16
  ushort_t* h1   = (ushort_t*)alloc(2097152);
  float*    c    = (float*)alloc(4194304);      // [B][H] fp32

  hipMemsetAsync(h0, 0, 2097152, stream);
  hipMemsetAsync(c, 0, 4194304, stream);

  k_prep<<<2048, 256, 0, stream>>>(wg, wi, wf, wo, wp, Whi, Wlo, w0, WPhi, WPlo);

  for (int t = 0; t < 64; ++t) {
    const ushort_t* ih = (t & 1) ? h1 : h0;
    ushort_t* oh = (t & 1) ? h0 : h1;
    k_step<<<256, 512, 0, stream>>>(Whi, Wlo, w0, x, bg, bi, bf, bo,
                                    ih, oh, c, t);
  }
  // after t=63 (odd) the freshest h lives in buffer 0
  k_proj<<<64, 256, 0, stream>>>(h0, WPhi, WPlo, bp, (float*)d_out);
}

// Round 5
// 1490.602 us; speedup vs baseline: 1.8647x; 1.0061x over previous
//
#include <hip/hip_runtime.h>

// LSTM_73512660239038: 64-step LSTM, H=B=1024, INPUT_DIM=1.
// R5: k_step K-loop -> triple-buffered LDS (3x48KB), counted s_waitcnt vmcnt(6)
// (T4), raw s_barrier (no full drain), setprio around MFMA (T5), full unroll.
// Numerics unchanged from R4: w = bf16 hi+lo (2 passes), h = single bf16.

typedef unsigned short ushort_t;
typedef __attribute__((ext_vector_type(8))) __bf16 bf16x8;
typedef __attribute__((ext_vector_type(4))) float f32x4;

typedef const __attribute__((address_space(1))) unsigned char* gbl_ptr_t;
typedef __attribute__((address_space(3))) unsigned char* lds_ptr_t;

__device__ __forceinline__ unsigned short f2bf(float f) {
  unsigned u = __float_as_uint(f);
  u += 0x7FFFu + ((u >> 16) & 1u);   // RNE
  return (unsigned short)(u >> 16);
}
__device__ __forceinline__ float bf2f(unsigned short b) {
  return __uint_as_float(((unsigned)b) << 16);
}
__device__ __forceinline__ float fsig(float z) {
  return 1.0f / (1.0f + __expf(-z));
}
__device__ __forceinline__ float ftanh(float z) {
  float a = fabsf(z);
  float e = __expf(-2.0f * a);
  float t = (1.0f - e) / (1.0f + e);
  return z < 0.0f ? -t : t;
}

// ---------------- prep: split weights into bf16 hi/lo ----------------
__global__ __launch_bounds__(256) void k_prep(
    const float* __restrict__ wg, const float* __restrict__ wi,
    const float* __restrict__ wf, const float* __restrict__ wo,
    const float* __restrict__ wp,
    ushort_t* __restrict__ Whi, ushort_t* __restrict__ Wlo,
    float* __restrict__ w0,
    ushort_t* __restrict__ WPhi, ushort_t* __restrict__ WPlo) {
  const int NW = 4 * 1024 * 1025;
  const int NP = 1024 * 1024;
  int i = blockIdx.x * blockDim.x + threadIdx.x;
  const int stride = gridDim.x * blockDim.x;
  for (; i < NW + NP; i += stride) {
    if (i < NW) {
      const int gate = i / (1024 * 1025);
      const int rem = i - gate * (1024 * 1025);
      const int r = rem / 1025;
      const int k = rem - r * 1025;
      const float* w = gate == 0 ? wg : gate == 1 ? wi : gate == 2 ? wf : wo;
      const float v = w[rem];
      if (k == 0) {
        w0[gate * 1024 + r] = v;
      } else {
        const int idx = (gate * 1024 + r) * 1024 + (k - 1);
        const unsigned short h = f2bf(v);
        Whi[idx] = h;
        Wlo[idx] = f2bf(v - bf2f(h));
      }
    } else {
      const int j = i - NW;
      const float v = wp[j];
      const unsigned short h = f2bf(v);
      WPhi[j] = h;
      WPlo[j] = f2bf(v - bf2f(h));
    }
  }
}

// ---------------- per-step fused kernel (R5: triple-buffer, counted vmcnt) ----
// grid 256: hrtile = bx&31 (32 h-rows), btile = bx>>5 (128 batch cols).
// 8 waves: gate = wid>>1 (A rows gate*32..+32), wn = wid&1 (B cols wn*64..+64).
// BK=64. LDS 144KB: 3 sets x {Whi,Wlo,H}[128][64]bf16 (48KB/set, SETB=49152).
// Schedule: iter kt stages kt+2, computes kt; vmcnt(6) + s_barrier per iter.
__global__ __launch_bounds__(512) void k_step(
    const ushort_t* __restrict__ Whi, const ushort_t* __restrict__ Wlo,
    const float* __restrict__ w0,
    const float* __restrict__ x,
    const float* __restrict__ bg, const float* __restrict__ bi,
    const float* __restrict__ bff, const float* __restrict__ bo,
    const ushort_t* __restrict__ Hin, ushort_t* __restrict__ Hout,
    float* __restrict__ c, int t) {
  __shared__ alignas(16) unsigned char smem[147456];
  const int tid = threadIdx.x;
  const int wid = tid >> 6;
  const int lane = tid & 63;
  const int gate = wid >> 1;                // A-row group AND output gate
  const int wn = wid & 1;                   // B-col half
  const int hr0 = (blockIdx.x & 31) * 32;
  const int b0 = (blockIdx.x >> 5) * 128;
  const unsigned SETB = 49152;

  // staging address precompute: chunks ch = s*512+tid, s=0..1 (1024 x 16B per tensor)
  long aoffb[2], boffb[2];
  int ldso[2];
#pragma unroll
  for (int s = 0; s < 2; ++s) {
    const int ch = s * 512 + tid;
    const int row = ch >> 3;
    const int sl = ch & 7;
    const int sg = sl ^ (row & 7);          // swizzle on the GLOBAL source
    const int gt = row >> 5, rin = row & 31;
    aoffb[s] = ((long)(gt * 1024 + hr0 + rin) << 10) + sg * 8;
    boffb[s] = ((long)(b0 + row) << 10) + sg * 8;
    ldso[s] = ch * 16;
  }

  f32x4 acc[2][4];
#pragma unroll
  for (int m = 0; m < 2; ++m)
#pragma unroll
    for (int n = 0; n < 4; ++n) acc[m][n] = (f32x4){0.f, 0.f, 0.f, 0.f};

  // prologue: stage buf0 (kt=0) and buf1 (kt=1) = 12 loads; wait oldest 6
#pragma unroll
  for (int p = 0; p < 2; ++p) {
    const unsigned nb = p * SETB;
    const int k0 = p << 6;
#pragma unroll
    for (int s = 0; s < 2; ++s) {
      __builtin_amdgcn_global_load_lds((gbl_ptr_t)(const void*)(Whi + aoffb[s] + k0),
                                       (lds_ptr_t)(void*)(smem + nb + ldso[s]), 16, 0, 0);
      __builtin_amdgcn_global_load_lds((gbl_ptr_t)(const void*)(Wlo + aoffb[s] + k0),
                                       (lds_ptr_t)(void*)(smem + nb + 16384 + ldso[s]), 16, 0, 0);
      __builtin_amdgcn_global_load_lds((gbl_ptr_t)(const void*)(Hin + boffb[s] + k0),
                                       (lds_ptr_t)(void*)(smem + nb + 32768 + ldso[s]), 16, 0, 0);
    }
  }
  asm volatile("s_waitcnt vmcnt(6)" ::: "memory");   // buf0 landed
  __builtin_amdgcn_s_barrier();
  asm volatile("" ::: "memory");

#pragma unroll
  for (int kt = 0; kt < 16; ++kt) {
    const unsigned pb = (unsigned)(kt % 3) * SETB;
    // ---- stage K-tile kt+2 into buf[(kt+2)%3] (issued BEFORE compute) ----
    if (kt < 14) {
      const unsigned nb = (unsigned)((kt + 2) % 3) * SETB;
      const int k0 = (kt + 2) << 6;
#pragma unroll
      for (int s = 0; s < 2; ++s) {
        __builtin_amdgcn_global_load_lds((gbl_ptr_t)(const void*)(Whi + aoffb[s] + k0),
                                         (lds_ptr_t)(void*)(smem + nb + ldso[s]), 16, 0, 0);
        __builtin_amdgcn_global_load_lds((gbl_ptr_t)(const void*)(Wlo + aoffb[s] + k0),
                                         (lds_ptr_t)(void*)(smem + nb + 16384 + ldso[s]), 16, 0, 0);
        __builtin_amdgcn_global_load_lds((gbl_ptr_t)(const void*)(Hin + boffb[s] + k0),
                                         (lds_ptr_t)(void*)(smem + nb + 32768 + ldso[s]), 16, 0, 0);
      }
    }
    // ---- compute buf[kt%3]: wave tile 32 (A rows) x 64 (B cols) ----
    __builtin_amdgcn_s_setprio(1);
#pragma unroll
    for (int ks = 0; ks < 2; ++ks) {
      const int slot = (ks << 2) + (lane >> 4);
      bf16x8 aH[2], aL[2];
#pragma unroll
      for (int m = 0; m < 2; ++m) {
        const int tra = gate * 32 + m * 16 + (lane & 15);
        const int offa = tra * 128 + ((slot ^ (tra & 7)) << 4);
        aH[m] = *(const bf16x8*)(smem + pb + offa);
        aL[m] = *(const bf16x8*)(smem + pb + 16384 + offa);
      }
#pragma unroll
      for (int n = 0; n < 4; ++n) {
        const int trb = wn * 64 + n * 16 + (lane & 15);
        const int offb = trb * 128 + ((slot ^ (trb & 7)) << 4);
        const bf16x8 bH = *(const bf16x8*)(smem + pb + 32768 + offb);
#pragma unroll
        for (int m = 0; m < 2; ++m) {
          acc[m][n] = __builtin_amdgcn_mfma_f32_16x16x32_bf16(aH[m], bH, acc[m][n], 0, 0, 0);
          acc[m][n] = __builtin_amdgcn_mfma_f32_16x16x32_bf16(aL[m], bH, acc[m][n], 0, 0, 0);
        }
      }
    }
    __builtin_amdgcn_s_setprio(0);
    // ---- counted drain: keep this iter's 6 loads in flight across barrier ----
    if (kt < 14) {
      asm volatile("s_waitcnt vmcnt(6)" ::: "memory");
    } else if (kt == 14) {
      asm volatile("s_waitcnt vmcnt(0)" ::: "memory");
    }
    if (kt < 15) {
      __builtin_amdgcn_s_barrier();
      asm volatile("" ::: "memory");
    }
  }
  __syncthreads();

  // ---- z exchange through LDS (swizzled r to dodge bank conflicts) ----
  float* zl = (float*)smem;                 // [4 gates][128 b][32 r] fp32 = 64KB
#pragma unroll
  for (int n = 0; n < 4; ++n) {
    const int b = wn * 64 + n * 16 + (lane & 15);
#pragma unroll
    for (int m = 0; m < 2; ++m) {
#pragma unroll
      for (int j = 0; j < 4; ++j) {
        const int r = m * 16 + (lane >> 4) * 4 + j;
        const int rs = (r ^ ((b & 7) << 2)) ^ ((b >> 3) & 1);
        zl[gate * 4096 + b * 32 + rs] = acc[m][n][j];
      }
    }
  }
  __syncthreads();
  // ---- elementwise gates; bias indexed by BATCH column (ref quirk) ----
  for (int q = 0; q < 8; ++q) {
    const int idx = q * 512 + tid;
    const int r = idx & 31, bb = idx >> 5;
    const int rs = (r ^ ((bb & 7) << 2)) ^ ((bb >> 3) & 1);
    const int gb = b0 + bb;
    const int gr = hr0 + r;
    float zg = zl[bb * 32 + rs];
    float zi = zl[4096 + bb * 32 + rs];
    float zf = zl[8192 + bb * 32 + rs];
    float zo = zl[12288 + bb * 32 + rs];
    const float xv = x[gb * 64 + t];
    zg += w0[gr] * xv + bg[gb];
    zi += w0[1024 + gr] * xv + bi[gb];
    zf += w0[2048 + gr] * xv + bff[gb];
    zo += w0[3072 + gr] * xv + bo[gb];
    const float g = ftanh(zg), ii = fsig(zi), ff = fsig(zf), oo = fsig(zo);
    const long ci = (long)gb * 1024 + gr;   // c and h stored [B][H]
    const float c2 = g * ii + c[ci] * ff;
    c[ci] = c2;
    const float h2 = ftanh(c2) * oo;
    Hout[ci] = f2bf(h2);
  }
}

// ---------------- final projection: out[b][r] = hs[b,:]·wp[r,:] + bp[r] ----------------
// h is single bf16; wp = hi+lo (2 passes).
__global__ __launch_bounds__(256) void k_proj(
    const ushort_t* __restrict__ H,
    const ushort_t* __restrict__ WPhi, const ushort_t* __restrict__ WPlo,
    const float* __restrict__ bp, float* __restrict__ out) {
  __shared__ alignas(16) unsigned char smem[49152];
  const int tid = threadIdx.x;
  const int wid = tid >> 6;
  const int lane = tid & 63;
  const int b0 = (blockIdx.x >> 3) * 128;   // M = batch
  const int r0 = (blockIdx.x & 7) * 128;    // N = output row

  f32x4 acc[2][8];
#pragma unroll
  for (int m = 0; m < 2; ++m)
#pragma unroll
    for (int n = 0; n < 8; ++n) acc[m][n] = (f32x4){0.f, 0.f, 0.f, 0.f};

  for (int kt = 0; kt < 16; ++kt) {
    const int k0 = kt << 6;
    __syncthreads();
#pragma unroll
    for (int j = 0; j < 4; ++j) {
      const int i = wid * 4 + j;
      const int ch = i * 64 + lane;
      const int row = ch >> 3;
      const int sl = ch & 7;
      const int sg = sl ^ (row & 7);
      const long aoff = ((long)(b0 + row) << 10) + k0 + sg * 8;
      const long boff = ((long)(r0 + row) << 10) + k0 + sg * 8;
      __builtin_amdgcn_global_load_lds((gbl_ptr_t)(const void*)(H + aoff),
                                       (lds_ptr_t)(void*)(smem + i * 1024), 16, 0, 0);
      __builtin_amdgcn_global_load_lds((gbl_ptr_t)(const void*)(WPhi + boff),
                                       (lds_ptr_t)(void*)(smem + 16384 + i * 1024), 16, 0, 0);
      __builtin_amdgcn_global_load_lds((gbl_ptr_t)(const void*)(WPlo + boff),
                                       (lds_ptr_t)(void*)(smem + 32768 + i * 1024), 16, 0, 0);
    }
    __syncthreads();
#pragma unroll
    for (int ks = 0; ks < 2; ++ks) {
      const int slot = (ks << 2) + (lane >> 4);
      bf16x8 aH[2];
#pragma unroll
      for (int m = 0; m < 2; ++m) {
        const int tr = wid * 32 + m * 16 + (lane & 15);
        const int off = tr * 128 + ((slot ^ (tr & 7)) << 4);
        aH[m] = *(const bf16x8*)(smem + off);
      }
#pragma unroll
      for (int n = 0; n < 8; ++n) {
        const int tr = n * 16 + (lane & 15);
        const int off = tr * 128 + ((slot ^ (tr & 7)) << 4);
        const bf16x8 bH = *(const bf16x8*)(smem + 16384 + off);
        const bf16x8 bL = *(const bf16x8*)(smem + 32768 + off);
#pragma unroll
        for (int m = 0; m < 2; ++m) {
          acc[m][n] = __builtin_amdgcn_mfma_f32_16x16x32_bf16(aH[m], bH, acc[m][n], 0, 0, 0);
          acc[m][n] = __builtin_amdgcn_mfma_f32_16x16x32_bf16(aH[m], bL, acc[m][n], 0, 0, 0);
        }
      }
    }
  }
#pragma unroll
  for (int n = 0; n < 8; ++n) {
    const int rr = r0 + n * 16 + (lane & 15);
    const float bpv = bp[rr];
#pragma unroll
    for (int m = 0; m < 2; ++m) {
#pragma unroll
      for (int j = 0; j < 4; ++j) {
        const int bbb = b0 + wid * 32 + m * 16 + (lane >> 4) * 4 + j;
        out[(long)bbb * 1024 + rr] = acc[m][n][j] + bpv;
      }
    }
  }
}

extern "C" void kernel_launch(void* const* d_in, const int* in_sizes, int n_in,
                              void* d_out, int out_size, void* d_ws, size_t ws_size,
                              hipStream_t stream) {
  (void)in_sizes; (void)n_in; (void)out_size; (void)ws_size;
  const float* x  = (const float*)d_in[0];
  const float* wg = (const float*)d_in[1];
  const float* bg = (const float*)d_in[2];
  const float* wi = (const float*)d_in[3];
  const float* bi = (const float*)d_in[4];
  const float* wf = (const float*)d_in[5];
  const float* bf = (const float*)d_in[6];
  const float* wo = (const float*)d_in[7];
  const float* bo = (const float*)d_in[8];
  const float* wp = (const float*)d_in[9];
  const float* bp = (const float*)d_in[10];

  char* ws = (char*)d_ws;
  size_t off = 0;
  auto alloc = [&](size_t bytes) {
    char* p = ws + off;
    off += (bytes + 255) & ~(size_t)255;
    return p;
  };
  ushort_t* Whi  = (ushort_t*)alloc(8388608);   // [4096][1024] bf16 hi
  ushort_t* Wlo  = (ushort_t*)alloc(8388608);
  ushort_t* WPhi = (ushort_t*)alloc(2097152);   // [1024][1024]
  ushort_t* WPlo = (ushort_t*)alloc(2097152);
  float*    w0   = (float*)alloc(16384);        // [4][1024] x-weight col
  ushort_t* h0   = (ushort_t*)alloc(2097152);   // h stored [B][H], single bf16
  ushort_t* h1   = (ushort_t*)alloc(2097152);
  float*    c    = (float*)alloc(4194304);      // [B][H] fp32

  hipMemsetAsync(h0, 0, 2097152, stream);
  hipMemsetAsync(c, 0, 4194304, stream);

  k_prep<<<2048, 256, 0, stream>>>(wg, wi, wf, wo, wp, Whi, Wlo, w0, WPhi, WPlo);

  for (int t = 0; t < 64; ++t) {
    const ushort_t* ih = (t & 1) ? h1 : h0;
    ushort_t* oh = (t & 1) ? h0 : h1;
    k_step<<<256, 512, 0, stream>>>(Whi, Wlo, w0, x, bg, bi, bf, bo,
                                    ih, oh, c, t);
  }
  // after t=63 (odd) the freshest h lives in buffer 0
  k_proj<<<64, 256, 0, stream>>>(h0, WPhi, WPlo, bp, (float*)d_out);
}

// Round 6
// 1134.230 us; speedup vs baseline: 2.4505x; 1.3142x over previous
//
#include <hip/hip_runtime.h>

// LSTM_73512660239038: 64-step LSTM, H=B=1024, INPUT_DIM=1.
// R6: numerics switched bf16-hi/lo -> SINGLE fp16 (e5m10). w,h,wp all fp16,
// accum fp32. Rel err 2^-11 vs bf16's 2^-8 => MORE accurate than R4/R5 AND
// single MFMA pass: LDS traffic 176->128 KB/iter, MFMA halves, staging halves.
// Keeps R5 schedule skeleton (3-buf LDS, counted vmcnt, setprio).

typedef _Float16 f16;
typedef __attribute__((ext_vector_type(8))) _Float16 f16x8;
typedef __attribute__((ext_vector_type(4))) float f32x4;

typedef const __attribute__((address_space(1))) unsigned char* gbl_ptr_t;
typedef __attribute__((address_space(3))) unsigned char* lds_ptr_t;

__device__ __forceinline__ float fsig(float z) {
  return 1.0f / (1.0f + __expf(-z));
}
__device__ __forceinline__ float ftanh(float z) {
  float a = fabsf(z);
  float e = __expf(-2.0f * a);
  float t = (1.0f - e) / (1.0f + e);
  return z < 0.0f ? -t : t;
}

// ---------------- prep: cast weights to fp16 (RNE) ----------------
__global__ __launch_bounds__(256) void k_prep(
    const float* __restrict__ wg, const float* __restrict__ wi,
    const float* __restrict__ wf, const float* __restrict__ wo,
    const float* __restrict__ wp,
    f16* __restrict__ Wf, float* __restrict__ w0,
    f16* __restrict__ WPf) {
  const int NW = 4 * 1024 * 1025;
  const int NP = 1024 * 1024;
  int i = blockIdx.x * blockDim.x + threadIdx.x;
  const int stride = gridDim.x * blockDim.x;
  for (; i < NW + NP; i += stride) {
    if (i < NW) {
      const int gate = i / (1024 * 1025);
      const int rem = i - gate * (1024 * 1025);
      const int r = rem / 1025;
      const int k = rem - r * 1025;
      const float* w = gate == 0 ? wg : gate == 1 ? wi : gate == 2 ? wf : wo;
      const float v = w[rem];
      if (k == 0) {
        w0[gate * 1024 + r] = v;            // x-weight column, kept fp32
      } else {
        Wf[(gate * 1024 + r) * 1024 + (k - 1)] = (f16)v;
      }
    } else {
      WPf[i - NW] = (f16)wp[i - NW];
    }
  }
}

// ---------------- per-step fused kernel (R6: fp16 single-pass) ----------------
// grid 256: hrtile = bx&31 (32 h-rows), btile = bx>>5 (128 batch cols).
// 8 waves: gate = wid>>1 (A rows gate*32..+32), wn = wid&1 (B cols wn*64..+64).
// BK=64. LDS 96KB: 3 sets x {Wf,H}[128][64]f16 (32KB/set, SETB=32768).
// Schedule: iter kt stages kt+2, computes kt; vmcnt(4) + s_barrier per iter.
__global__ __launch_bounds__(512) void k_step(
    const f16* __restrict__ Wf,
    const float* __restrict__ w0,
    const float* __restrict__ x,
    const float* __restrict__ bg, const float* __restrict__ bi,
    const float* __restrict__ bff, const float* __restrict__ bo,
    const f16* __restrict__ Hin, f16* __restrict__ Hout,
    float* __restrict__ c, int t) {
  __shared__ alignas(16) unsigned char smem[98304];
  const int tid = threadIdx.x;
  const int wid = tid >> 6;
  const int lane = tid & 63;
  const int gate = wid >> 1;                // A-row group AND output gate
  const int wn = wid & 1;                   // B-col half
  const int hr0 = (blockIdx.x & 31) * 32;
  const int b0 = (blockIdx.x >> 5) * 128;
  const unsigned SETB = 32768;

  // staging address precompute: chunks ch = s*512+tid, s=0..1 (1024 x 16B per tensor)
  long aoffb[2], boffb[2];
  int ldso[2];
#pragma unroll
  for (int s = 0; s < 2; ++s) {
    const int ch = s * 512 + tid;
    const int row = ch >> 3;
    const int sl = ch & 7;
    const int sg = sl ^ (row & 7);          // swizzle on the GLOBAL source
    const int gt = row >> 5, rin = row & 31;
    aoffb[s] = ((long)(gt * 1024 + hr0 + rin) << 10) + sg * 8;
    boffb[s] = ((long)(b0 + row) << 10) + sg * 8;
    ldso[s] = ch * 16;
  }

  f32x4 acc[2][4];
#pragma unroll
  for (int m = 0; m < 2; ++m)
#pragma unroll
    for (int n = 0; n < 4; ++n) acc[m][n] = (f32x4){0.f, 0.f, 0.f, 0.f};

  // prologue: stage buf0 (kt=0) and buf1 (kt=1) = 8 loads; wait oldest 4
#pragma unroll
  for (int p = 0; p < 2; ++p) {
    const unsigned nb = p * SETB;
    const int k0 = p << 6;
#pragma unroll
    for (int s = 0; s < 2; ++s) {
      __builtin_amdgcn_global_load_lds((gbl_ptr_t)(const void*)(Wf + aoffb[s] + k0),
                                       (lds_ptr_t)(void*)(smem + nb + ldso[s]), 16, 0, 0);
      __builtin_amdgcn_global_load_lds((gbl_ptr_t)(const void*)(Hin + boffb[s] + k0),
                                       (lds_ptr_t)(void*)(smem + nb + 16384 + ldso[s]), 16, 0, 0);
    }
  }
  asm volatile("s_waitcnt vmcnt(4)" ::: "memory");   // buf0 landed
  __builtin_amdgcn_s_barrier();
  asm volatile("" ::: "memory");

#pragma unroll
  for (int kt = 0; kt < 16; ++kt) {
    const unsigned pb = (unsigned)(kt % 3) * SETB;
    // ---- stage K-tile kt+2 into buf[(kt+2)%3] (issued BEFORE compute) ----
    if (kt < 14) {
      const unsigned nb = (unsigned)((kt + 2) % 3) * SETB;
      const int k0 = (kt + 2) << 6;
#pragma unroll
      for (int s = 0; s < 2; ++s) {
        __builtin_amdgcn_global_load_lds((gbl_ptr_t)(const void*)(Wf + aoffb[s] + k0),
                                         (lds_ptr_t)(void*)(smem + nb + ldso[s]), 16, 0, 0);
        __builtin_amdgcn_global_load_lds((gbl_ptr_t)(const void*)(Hin + boffb[s] + k0),
                                         (lds_ptr_t)(void*)(smem + nb + 16384 + ldso[s]), 16, 0, 0);
      }
    }
    // ---- compute buf[kt%3]: wave tile 32 (A rows) x 64 (B cols) ----
    __builtin_amdgcn_s_setprio(1);
#pragma unroll
    for (int ks = 0; ks < 2; ++ks) {
      const int slot = (ks << 2) + (lane >> 4);
      f16x8 aF[2];
#pragma unroll
      for (int m = 0; m < 2; ++m) {
        const int tra = gate * 32 + m * 16 + (lane & 15);
        const int offa = tra * 128 + ((slot ^ (tra & 7)) << 4);
        aF[m] = *(const f16x8*)(smem + pb + offa);
      }
#pragma unroll
      for (int n = 0; n < 4; ++n) {
        const int trb = wn * 64 + n * 16 + (lane & 15);
        const int offb = trb * 128 + ((slot ^ (trb & 7)) << 4);
        const f16x8 bF = *(const f16x8*)(smem + pb + 16384 + offb);
#pragma unroll
        for (int m = 0; m < 2; ++m) {
          acc[m][n] = __builtin_amdgcn_mfma_f32_16x16x32_f16(aF[m], bF, acc[m][n], 0, 0, 0);
        }
      }
    }
    __builtin_amdgcn_s_setprio(0);
    // ---- counted drain: keep this iter's 4 loads in flight across barrier ----
    if (kt < 14) {
      asm volatile("s_waitcnt vmcnt(4)" ::: "memory");
    } else if (kt == 14) {
      asm volatile("s_waitcnt vmcnt(0)" ::: "memory");
    }
    if (kt < 15) {
      __builtin_amdgcn_s_barrier();
      asm volatile("" ::: "memory");
    }
  }
  __syncthreads();

  // ---- z exchange through LDS (swizzled r to dodge bank conflicts) ----
  float* zl = (float*)smem;                 // [4 gates][128 b][32 r] fp32 = 64KB
#pragma unroll
  for (int n = 0; n < 4; ++n) {
    const int b = wn * 64 + n * 16 + (lane & 15);
#pragma unroll
    for (int m = 0; m < 2; ++m) {
#pragma unroll
      for (int j = 0; j < 4; ++j) {
        const int r = m * 16 + (lane >> 4) * 4 + j;
        const int rs = (r ^ ((b & 7) << 2)) ^ ((b >> 3) & 1);
        zl[gate * 4096 + b * 32 + rs] = acc[m][n][j];
      }
    }
  }
  __syncthreads();
  // ---- elementwise gates; bias indexed by BATCH column (ref quirk) ----
  for (int q = 0; q < 8; ++q) {
    const int idx = q * 512 + tid;
    const int r = idx & 31, bb = idx >> 5;
    const int rs = (r ^ ((bb & 7) << 2)) ^ ((bb >> 3) & 1);
    const int gb = b0 + bb;
    const int gr = hr0 + r;
    float zg = zl[bb * 32 + rs];
    float zi = zl[4096 + bb * 32 + rs];
    float zf = zl[8192 + bb * 32 + rs];
    float zo = zl[12288 + bb * 32 + rs];
    const float xv = x[gb * 64 + t];
    zg += w0[gr] * xv + bg[gb];
    zi += w0[1024 + gr] * xv + bi[gb];
    zf += w0[2048 + gr] * xv + bff[gb];
    zo += w0[3072 + gr] * xv + bo[gb];
    const float g = ftanh(zg), ii = fsig(zi), ff = fsig(zf), oo = fsig(zo);
    const long ci = (long)gb * 1024 + gr;   // c and h stored [B][H]
    const float c2 = g * ii + c[ci] * ff;
    c[ci] = c2;
    const float h2 = ftanh(c2) * oo;
    Hout[ci] = (f16)h2;
  }
}

// ---------------- final projection: out[b][r] = hs[b,:]·wp[r,:] + bp[r] ----------------
// single-pass fp16.
__global__ __launch_bounds__(256) void k_proj(
    const f16* __restrict__ H, const f16* __restrict__ WPf,
    const float* __restrict__ bp, float* __restrict__ out) {
  __shared__ alignas(16) unsigned char smem[32768];
  const int tid = threadIdx.x;
  const int wid = tid >> 6;
  const int lane = tid & 63;
  const int b0 = (blockIdx.x >> 3) * 128;   // M = batch
  const int r0 = (blockIdx.x & 7) * 128;    // N = output row

  f32x4 acc[2][8];
#pragma unroll
  for (int m = 0; m < 2; ++m)
#pragma unroll
    for (int n = 0; n < 8; ++n) acc[m][n] = (f32x4){0.f, 0.f, 0.f, 0.f};

  for (int kt = 0; kt < 16; ++kt) {
    const int k0 = kt << 6;
    __syncthreads();
#pragma unroll
    for (int j = 0; j < 4; ++j) {
      const int i = wid * 4 + j;
      const int ch = i * 64 + lane;
      const int row = ch >> 3;
      const int sl = ch & 7;
      const int sg = sl ^ (row & 7);
      const long aoff = ((long)(b0 + row) << 10) + k0 + sg * 8;
      const long boff = ((long)(r0 + row) << 10) + k0 + sg * 8;
      __builtin_amdgcn_global_load_lds((gbl_ptr_t)(const void*)(H + aoff),
                                       (lds_ptr_t)(void*)(smem + i * 1024), 16, 0, 0);
      __builtin_amdgcn_global_load_lds((gbl_ptr_t)(const void*)(WPf + boff),
                                       (lds_ptr_t)(void*)(smem + 16384 + i * 1024), 16, 0, 0);
    }
    __syncthreads();
#pragma unroll
    for (int ks = 0; ks < 2; ++ks) {
      const int slot = (ks << 2) + (lane >> 4);
      f16x8 aF[2];
#pragma unroll
      for (int m = 0; m < 2; ++m) {
        const int tr = wid * 32 + m * 16 + (lane & 15);
        const int off = tr * 128 + ((slot ^ (tr & 7)) << 4);
        aF[m] = *(const f16x8*)(smem + off);
      }
#pragma unroll
      for (int n = 0; n < 8; ++n) {
        const int tr = n * 16 + (lane & 15);
        const int off = tr * 128 + ((slot ^ (tr & 7)) << 4);
        const f16x8 bF = *(const f16x8*)(smem + 16384 + off);
#pragma unroll
        for (int m = 0; m < 2; ++m) {
          acc[m][n] = __builtin_amdgcn_mfma_f32_16x16x32_f16(aF[m], bF, acc[m][n], 0, 0, 0);
        }
      }
    }
  }
#pragma unroll
  for (int n = 0; n < 8; ++n) {
    const int rr = r0 + n * 16 + (lane & 15);
    const float bpv = bp[rr];
#pragma unroll
    for (int m = 0; m < 2; ++m) {
#pragma unroll
      for (int j = 0; j < 4; ++j) {
        const int bbb = b0 + wid * 32 + m * 16 + (lane >> 4) * 4 + j;
        out[(long)bbb * 1024 + rr] = acc[m][n][j] + bpv;
      }
    }
  }
}

extern "C" void kernel_launch(void* const* d_in, const int* in_sizes, int n_in,
                              void* d_out, int out_size, void* d_ws, size_t ws_size,
                              hipStream_t stream) {
  (void)in_sizes; (void)n_in; (void)out_size; (void)ws_size;
  const float* x  = (const float*)d_in[0];
  const float* wg = (const float*)d_in[1];
  const float* bg = (const float*)d_in[2];
  const float* wi = (const float*)d_in[3];
  const float* bi = (const float*)d_in[4];
  const float* wf = (const float*)d_in[5];
  const float* bf = (const float*)d_in[6];
  const float* wo = (const float*)d_in[7];
  const float* bo = (const float*)d_in[8];
  const float* wp = (const float*)d_in[9];
  const float* bp = (const float*)d_in[10];

  char* ws = (char*)d_ws;
  size_t off = 0;
  auto alloc = [&](size_t bytes) {
    char* p = ws + off;
    off += (bytes + 255) & ~(size_t)255;
    return p;
  };
  f16*   Wf  = (f16*)alloc(8388608);    // [4096][1024] fp16
  f16*   WPf = (f16*)alloc(2097152);    // [1024][1024] fp16
  float* w0  = (float*)alloc(16384);    // [4][1024] x-weight col fp32
  f16*   h0  = (f16*)alloc(2097152);    // h stored [B][H] fp16
  f16*   h1  = (f16*)alloc(2097152);
  float* c   = (float*)alloc(4194304);  // [B][H] fp32

  hipMemsetAsync(h0, 0, 2097152, stream);
  hipMemsetAsync(c, 0, 4194304, stream);

  k_prep<<<2048, 256, 0, stream>>>(wg, wi, wf, wo, wp, Wf, w0, WPf);

  for (int t = 0; t < 64; ++t) {
    const f16* ih = (t & 1) ? h1 : h0;
    f16* oh = (t & 1) ? h0 : h1;
    k_step<<<256, 512, 0, stream>>>(Wf, w0, x, bg, bi, bf, bo, ih, oh, c, t);
  }
  // after t=63 (odd) the freshest h lives in buffer 0
  k_proj<<<64, 256, 0, stream>>>(h0, WPf, bp, (float*)d_out);
}